// Round 1
// baseline (3308.591 us; speedup 1.0000x reference)
//
#include <hip/hip_runtime.h>
#include <stdint.h>

#define NN 50000
#define NE 800000
#define HD 64
#define OD 128
#define NL 4

static __device__ __forceinline__ unsigned short f2bf(float f) {
    unsigned int u = __float_as_uint(f);
    u += 0x7fffu + ((u >> 16) & 1u);   // round-to-nearest-even
    return (unsigned short)(u >> 16);
}
static __device__ __forceinline__ float bf2f(unsigned short s) {
    return __uint_as_float(((unsigned int)s) << 16);
}

// h = x @ in_w + in_b   (wave per node, lane = channel)
__global__ __launch_bounds__(256) void k_input(const float* __restrict__ x,
        const float* __restrict__ in_w, const float* __restrict__ in_b,
        float* __restrict__ h) {
    int n = blockIdx.x * 4 + (threadIdx.x >> 6);
    int k = threadIdx.x & 63;
    const float* xr = x + (size_t)n * 3;
    float v = in_b[k] + xr[0] * in_w[k] + xr[1] * in_w[64 + k] + xr[2] * in_w[128 + k];
    h[(size_t)n * 64 + k] = v;
}

// edge_attr = relu(rel_pos @ ew1 + eb1) @ ew2 + eb2, stored bf16.
// 64-edge x 64-channel tile per block; t kept transposed in LDS.
__global__ __launch_bounds__(256) void k_edge(const float* __restrict__ x,
        const int* __restrict__ ei,
        const float* __restrict__ ew1, const float* __restrict__ eb1,
        const float* __restrict__ ew2, const float* __restrict__ eb2,
        unsigned short* __restrict__ ea) {
    __shared__ float s_w2[64 * 64];
    __shared__ float s_tT[64 * 64];   // [j][edge]
    __shared__ float s_w1[128];
    __shared__ float s_b1[64];
    __shared__ float s_b2[64];
    int tid = threadIdx.x;
    for (int i = tid; i < 4096; i += 256) s_w2[i] = ew2[i];
    if (tid < 128) s_w1[tid] = ew1[tid];
    if (tid < 64) s_b1[tid] = eb1[tid];
    else if (tid < 128) s_b2[tid - 64] = eb2[tid - 64];
    __syncthreads();

    int e0 = blockIdx.x * 64;
    int et = tid & 63;
    int jb = tid >> 6;
    int e = e0 + et;
    int r = ei[e], c = ei[NE + e];
    float rx = x[(size_t)c * 3]     - x[(size_t)r * 3];
    float ry = x[(size_t)c * 3 + 1] - x[(size_t)r * 3 + 1];
    #pragma unroll
    for (int jj = 0; jj < 16; ++jj) {
        int j = jb * 16 + jj;
        float t = fmaxf(rx * s_w1[j] + ry * s_w1[64 + j] + s_b1[j], 0.f);
        s_tT[j * 64 + et] = t;
    }
    __syncthreads();

    int er = (tid >> 4) << 2;   // 4 edges per thread
    int cc = (tid & 15) << 2;   // 4 channels per thread
    float4 acc0 = {0,0,0,0}, acc1 = {0,0,0,0}, acc2 = {0,0,0,0}, acc3 = {0,0,0,0};
    #pragma unroll 8
    for (int k = 0; k < 64; ++k) {
        float4 w = *(const float4*)&s_w2[k * 64 + cc];
        float4 t = *(const float4*)&s_tT[k * 64 + er];
        acc0.x += t.x * w.x; acc0.y += t.x * w.y; acc0.z += t.x * w.z; acc0.w += t.x * w.w;
        acc1.x += t.y * w.x; acc1.y += t.y * w.y; acc1.z += t.y * w.z; acc1.w += t.y * w.w;
        acc2.x += t.z * w.x; acc2.y += t.z * w.y; acc2.z += t.z * w.z; acc2.w += t.z * w.w;
        acc3.x += t.w * w.x; acc3.y += t.w * w.y; acc3.z += t.w * w.z; acc3.w += t.w * w.w;
    }
    float4 b2 = *(const float4*)&s_b2[cc];
    float4 accs[4] = {acc0, acc1, acc2, acc3};
    #pragma unroll
    for (int i = 0; i < 4; ++i) {
        ushort4 o;
        o.x = f2bf(accs[i].x + b2.x);
        o.y = f2bf(accs[i].y + b2.y);
        o.z = f2bf(accs[i].z + b2.z);
        o.w = f2bf(accs[i].w + b2.w);
        *(ushort4*)&ea[(size_t)(e0 + er + i) * 64 + cc] = o;
    }
}

// agg[col] += relu(h[row] + edge_attr)   (16 threads per edge, 4 ch each)
__global__ __launch_bounds__(256) void k_msg(const float* __restrict__ h,
        const unsigned short* __restrict__ ea, const int* __restrict__ ei,
        float* __restrict__ agg) {
    int t = blockIdx.x * 256 + threadIdx.x;
    int e = t >> 4;
    int c = (t & 15) << 2;
    int r = ei[e];
    int col = ei[NE + e];
    float4 hv = *(const float4*)&h[(size_t)r * 64 + c];
    ushort4 ev = *(const ushort4*)&ea[(size_t)e * 64 + c];
    float m0 = fmaxf(hv.x + bf2f(ev.x), 0.f);
    float m1 = fmaxf(hv.y + bf2f(ev.y), 0.f);
    float m2 = fmaxf(hv.z + bf2f(ev.z), 0.f);
    float m3 = fmaxf(hv.w + bf2f(ev.w), 0.f);
    float* ag = agg + (size_t)col * 64 + c;
    atomicAdd(ag + 0, m0);
    atomicAdd(ag + 1, m1);
    atomicAdd(ag + 2, m2);
    atomicAdd(ag + 3, m3);
}

// fused: m = h + agg; m = relu(m@cw1+cb1)@cw2+cb2; LN; h = gelu(m) + h
// wave per node, lane = channel; weights transposed in LDS (stride 68)
__global__ __launch_bounds__(256) void k_node(float* __restrict__ h,
        const float* __restrict__ agg,
        const float* __restrict__ cw1, const float* __restrict__ cb1,
        const float* __restrict__ cw2, const float* __restrict__ cb2,
        const float* __restrict__ lnw, const float* __restrict__ lnb) {
    __shared__ float s_w1t[64 * 68];
    __shared__ float s_w2t[64 * 68];
    __shared__ float s_b1[64], s_b2[64], s_g[64], s_bt[64];
    __shared__ float s_m[4][64];
    int tid = threadIdx.x;
    for (int i = tid; i < 4096; i += 256) {
        int kk = i >> 6, k = i & 63;
        s_w1t[k * 68 + kk] = cw1[i];
        s_w2t[k * 68 + kk] = cw2[i];
    }
    if (tid < 64) { s_b1[tid] = cb1[tid]; s_g[tid] = lnw[tid]; }
    else if (tid < 128) { s_b2[tid - 64] = cb2[tid - 64]; s_bt[tid - 64] = lnb[tid - 64]; }
    __syncthreads();

    int w = tid >> 6, k = tid & 63;
    int n = blockIdx.x * 4 + w;
    float identity = h[(size_t)n * 64 + k];
    float m = identity + agg[(size_t)n * 64 + k];
    s_m[w][k] = m;
    __syncthreads();

    float acc = s_b1[k];
    {
        const float4* wr = (const float4*)&s_w1t[k * 68];
        const float4* mr = (const float4*)&s_m[w][0];
        #pragma unroll
        for (int q = 0; q < 16; ++q) {
            float4 wv = wr[q], mv = mr[q];
            acc += mv.x * wv.x + mv.y * wv.y + mv.z * wv.z + mv.w * wv.w;
        }
    }
    float u = fmaxf(acc, 0.f);
    __syncthreads();
    s_m[w][k] = u;
    __syncthreads();

    float acc2 = s_b2[k];
    {
        const float4* wr = (const float4*)&s_w2t[k * 68];
        const float4* mr = (const float4*)&s_m[w][0];
        #pragma unroll
        for (int q = 0; q < 16; ++q) {
            float4 wv = wr[q], mv = mr[q];
            acc2 += mv.x * wv.x + mv.y * wv.y + mv.z * wv.z + mv.w * wv.w;
        }
    }
    float v = acc2;
    float sum = v, sq = v * v;
    #pragma unroll
    for (int off = 32; off > 0; off >>= 1) {
        sum += __shfl_xor(sum, off, 64);
        sq  += __shfl_xor(sq, off, 64);
    }
    float mu  = sum * (1.f / 64.f);
    float var = sq * (1.f / 64.f) - mu * mu;
    float y = (v - mu) * rsqrtf(var + 1e-5f) * s_g[k] + s_bt[k];
    float ge = 0.5f * y * (1.f + erff(y * 0.70710678118654752f));
    h[(size_t)n * 64 + k] = ge + identity;
}

// out = LN( h@(fw+rw) + (fb+rb) ; ow, ob )   (2 nodes per block, 128 thr/node)
__global__ __launch_bounds__(256) void k_final(const float* __restrict__ h,
        const float* __restrict__ fw, const float* __restrict__ fb,
        const float* __restrict__ rw, const float* __restrict__ rb,
        const float* __restrict__ ow, const float* __restrict__ ob,
        float* __restrict__ out) {
    __shared__ float s_wT[128 * 68];   // [c][k], combined fw+rw
    __shared__ float s_b[128];
    __shared__ float s_h[2][64];
    __shared__ float s_red[4][2];
    int tid = threadIdx.x;
    for (int i = tid; i < 8192; i += 256) {
        int k = i >> 7, c = i & 127;
        s_wT[c * 68 + k] = fw[i] + rw[i];
    }
    if (tid < 128) s_b[tid] = fb[tid] + rb[tid];
    int half = tid >> 7, c = tid & 127;
    int n = blockIdx.x * 2 + half;
    if (c < 64) s_h[half][c] = h[(size_t)n * 64 + c];
    __syncthreads();

    float acc = s_b[c];
    const float4* wr = (const float4*)&s_wT[c * 68];
    const float4* hr = (const float4*)&s_h[half][0];
    #pragma unroll
    for (int q = 0; q < 16; ++q) {
        float4 wv = wr[q], hv = hr[q];
        acc += hv.x * wv.x + hv.y * wv.y + hv.z * wv.z + hv.w * wv.w;
    }
    float v = acc;
    float sum = v, sq = v * v;
    #pragma unroll
    for (int off = 32; off > 0; off >>= 1) {
        sum += __shfl_xor(sum, off, 64);
        sq  += __shfl_xor(sq, off, 64);
    }
    int wid = tid >> 6;
    if ((tid & 63) == 0) { s_red[wid][0] = sum; s_red[wid][1] = sq; }
    __syncthreads();
    float tsum = s_red[half * 2][0] + s_red[half * 2 + 1][0];
    float tsq  = s_red[half * 2][1] + s_red[half * 2 + 1][1];
    float mu  = tsum * (1.f / 128.f);
    float var = tsq * (1.f / 128.f) - mu * mu;
    float y = (v - mu) * rsqrtf(var + 1e-5f) * ow[c] + ob[c];
    out[(size_t)n * 128 + c] = y;
}

extern "C" void kernel_launch(void* const* d_in, const int* in_sizes, int n_in,
                              void* d_out, int out_size, void* d_ws, size_t ws_size,
                              hipStream_t stream) {
    const float* x    = (const float*)d_in[0];
    const int*   ei   = (const int*)d_in[1];
    const float* in_w = (const float*)d_in[2];
    const float* in_b = (const float*)d_in[3];
    const float* ew1  = (const float*)d_in[4];
    const float* eb1  = (const float*)d_in[5];
    const float* ew2  = (const float*)d_in[6];
    const float* eb2  = (const float*)d_in[7];
    const float* cw1  = (const float*)d_in[8];
    const float* cb1  = (const float*)d_in[9];
    const float* cw2  = (const float*)d_in[10];
    const float* cb2  = (const float*)d_in[11];
    const float* lnw  = (const float*)d_in[12];
    const float* lnb  = (const float*)d_in[13];
    const float* fw   = (const float*)d_in[14];
    const float* fb   = (const float*)d_in[15];
    const float* rw   = (const float*)d_in[16];
    const float* rb   = (const float*)d_in[17];
    const float* ow   = (const float*)d_in[18];
    const float* ob   = (const float*)d_in[19];
    float* out = (float*)d_out;

    // workspace layout (all 16B-aligned):
    //   ea  : NE*64 bf16  = 102,400,000 B
    //   h   : NN*64 f32   =  12,800,000 B
    //   agg : NN*64 f32   =  12,800,000 B
    char* ws = (char*)d_ws;
    unsigned short* ea = (unsigned short*)ws;
    float* h   = (float*)(ws + 102400000);
    float* agg = (float*)(ws + 102400000 + 12800000);

    k_input<<<NN / 4, 256, 0, stream>>>(x, in_w, in_b, h);
    k_edge<<<NE / 64, 256, 0, stream>>>(x, ei, ew1, eb1, ew2, eb2, ea);
    for (int l = 0; l < NL; ++l) {
        hipMemsetAsync(agg, 0, (size_t)NN * 64 * 4, stream);
        k_msg<<<(NE * 16) / 256, 256, 0, stream>>>(h, ea, ei, agg);
        k_node<<<NN / 4, 256, 0, stream>>>(h, agg,
            cw1 + (size_t)l * 4096, cb1 + (size_t)l * 64,
            cw2 + (size_t)l * 4096, cb2 + (size_t)l * 64,
            lnw + (size_t)l * 64,   lnb + (size_t)l * 64);
    }
    k_final<<<NN / 2, 256, 0, stream>>>(h, fw, fb, rw, rb, ow, ob, out);
}

// Round 2
// 867.156 us; speedup vs baseline: 3.8155x; 3.8155x over previous
//
#include <hip/hip_runtime.h>
#include <hip/hip_fp16.h>
#include <stdint.h>

#define NN 50000
#define NE 800000

static __device__ __forceinline__ unsigned short f2bf(float f) {
    unsigned int u = __float_as_uint(f);
    u += 0x7fffu + ((u >> 16) & 1u);   // round-to-nearest-even
    return (unsigned short)(u >> 16);
}
static __device__ __forceinline__ float bf2f(unsigned short s) {
    return __uint_as_float(((unsigned int)s) << 16);
}
static __device__ __forceinline__ float toF(float v) { return v; }
static __device__ __forceinline__ float toF(__half v) { return __half2float(v); }
static __device__ __forceinline__ void fromF(float& d, float v) { d = v; }
static __device__ __forceinline__ void fromF(__half& d, float v) { d = __float2half(v); }

// ---------- CSR build ----------
__global__ __launch_bounds__(256) void k_deg(const int* __restrict__ ei, int* __restrict__ offcur) {
    int e = blockIdx.x * 256 + threadIdx.x;
    atomicAdd(&offcur[ei[NE + e]], 1);
}

// in-place exclusive scan of offcur[0..NN), offcur[NN]=total. one block, 1024 thr.
__global__ __launch_bounds__(1024) void k_scan(int* __restrict__ offcur) {
    __shared__ int s[1024];
    const int C = (NN + 1023) / 1024;   // 49
    int t = threadIdx.x;
    int base = t * C;
    int sum = 0;
    for (int i = 0; i < C; ++i) { int idx = base + i; if (idx < NN) sum += offcur[idx]; }
    s[t] = sum; __syncthreads();
    for (int d = 1; d < 1024; d <<= 1) {
        int v = (t >= d) ? s[t - d] : 0;
        __syncthreads();
        s[t] += v;
        __syncthreads();
    }
    int run = (t > 0) ? s[t - 1] : 0;
    for (int i = 0; i < C; ++i) {
        int idx = base + i;
        if (idx < NN) { int d = offcur[idx]; offcur[idx] = run; run += d; }
    }
    if (t == 1023) offcur[NN] = s[1023];
}

// pos = offcur[col]++ ; rows[pos] = row (u16) ; dpos[e] = pos
// after this kernel offcur[n] == CSR end-offset of node n.
__global__ __launch_bounds__(256) void k_scatter(const int* __restrict__ ei,
        int* __restrict__ offcur, unsigned short* __restrict__ rows, int* __restrict__ dpos) {
    int e = blockIdx.x * 256 + threadIdx.x;
    int col = ei[NE + e];
    int pos = atomicAdd(&offcur[col], 1);
    rows[pos] = (unsigned short)ei[e];
    dpos[e] = pos;
}

// ---------- h init ----------
__global__ __launch_bounds__(256) void k_input(const float* __restrict__ x,
        const float* __restrict__ in_w, const float* __restrict__ in_b,
        float* __restrict__ h) {
    int n = blockIdx.x * 4 + (threadIdx.x >> 6);
    int k = threadIdx.x & 63;
    const float* xr = x + (size_t)n * 3;
    h[(size_t)n * 64 + k] = in_b[k] + xr[0] * in_w[k] + xr[1] * in_w[64 + k] + xr[2] * in_w[128 + k];
}

// ---------- edge MLP -> ea (bf16), written in dest-sorted order ----------
__global__ __launch_bounds__(256) void k_edge(const float* __restrict__ x,
        const int* __restrict__ ei,
        const float* __restrict__ ew1, const float* __restrict__ eb1,
        const float* __restrict__ ew2, const float* __restrict__ eb2,
        const int* __restrict__ dpos, unsigned short* __restrict__ ea) {
    __shared__ float s_w2[64 * 64];
    __shared__ float s_tT[64 * 64];   // [j][edge]
    __shared__ float s_w1[128];
    __shared__ float s_b1[64];
    __shared__ float s_b2[64];
    int tid = threadIdx.x;
    for (int i = tid; i < 4096; i += 256) s_w2[i] = ew2[i];
    if (tid < 128) s_w1[tid] = ew1[tid];
    if (tid < 64) s_b1[tid] = eb1[tid];
    else if (tid < 128) s_b2[tid - 64] = eb2[tid - 64];
    __syncthreads();

    int e0 = blockIdx.x * 64;
    int et = tid & 63;
    int jb = tid >> 6;
    int e = e0 + et;
    int r = ei[e], c = ei[NE + e];
    float rx = x[(size_t)c * 3]     - x[(size_t)r * 3];
    float ry = x[(size_t)c * 3 + 1] - x[(size_t)r * 3 + 1];
    #pragma unroll
    for (int jj = 0; jj < 16; ++jj) {
        int j = jb * 16 + jj;
        float t = fmaxf(rx * s_w1[j] + ry * s_w1[64 + j] + s_b1[j], 0.f);
        s_tT[j * 64 + et] = t;
    }
    __syncthreads();

    int er = (tid >> 4) << 2;   // 4 edges per thread
    int cc = (tid & 15) << 2;   // 4 channels per thread
    float4 acc0 = {0,0,0,0}, acc1 = {0,0,0,0}, acc2 = {0,0,0,0}, acc3 = {0,0,0,0};
    #pragma unroll 8
    for (int k = 0; k < 64; ++k) {
        float4 w = *(const float4*)&s_w2[k * 64 + cc];
        float4 t = *(const float4*)&s_tT[k * 64 + er];
        acc0.x += t.x * w.x; acc0.y += t.x * w.y; acc0.z += t.x * w.z; acc0.w += t.x * w.w;
        acc1.x += t.y * w.x; acc1.y += t.y * w.y; acc1.z += t.y * w.z; acc1.w += t.y * w.w;
        acc2.x += t.z * w.x; acc2.y += t.z * w.y; acc2.z += t.z * w.z; acc2.w += t.z * w.w;
        acc3.x += t.w * w.x; acc3.y += t.w * w.y; acc3.z += t.w * w.z; acc3.w += t.w * w.w;
    }
    float4 b2 = *(const float4*)&s_b2[cc];
    float4 accs[4] = {acc0, acc1, acc2, acc3};
    #pragma unroll
    for (int i = 0; i < 4; ++i) {
        int pos = dpos[e0 + er + i];
        ushort4 o;
        o.x = f2bf(accs[i].x + b2.x);
        o.y = f2bf(accs[i].y + b2.y);
        o.z = f2bf(accs[i].z + b2.z);
        o.w = f2bf(accs[i].w + b2.w);
        *(ushort4*)&ea[(size_t)pos * 64 + cc] = o;
    }
}

// ---------- per-layer: gather aggregate (atomic-free) ----------
// M[n] = h[n] + sum_{p in [p0,p1)} relu(h[rows[p]] + ea[p])
template <typename MT>
__global__ __launch_bounds__(256) void k_agg(const float* __restrict__ A,
        const unsigned short* __restrict__ ea, const unsigned short* __restrict__ rows,
        const int* __restrict__ offcur, MT* __restrict__ M) {
    int w = threadIdx.x >> 6, k = threadIdx.x & 63;
    int n = blockIdx.x * 4 + w;
    int p0 = (n == 0) ? 0 : offcur[n - 1];
    int p1 = offcur[n];
    float acc = A[(size_t)n * 64 + k];
    for (int base = p0; base < p1; base += 64) {
        int cnt = min(64, p1 - base);
        int rl = (k < cnt) ? (int)rows[base + k] : 0;
        #pragma unroll 4
        for (int j = 0; j < cnt; ++j) {
            int r = __shfl(rl, j, 64);
            float hv = A[(size_t)r * 64 + k];
            float ev = bf2f(ea[(size_t)(base + j) * 64 + k]);
            acc += fmaxf(hv + ev, 0.f);
        }
    }
    fromF(M[(size_t)n * 64 + k], acc);
}

// ---------- per-layer: node MLP + LN + gelu + residual, in-place on A ----------
template <typename MT>
__global__ __launch_bounds__(256) void k_node(float* __restrict__ A, const MT* __restrict__ M,
        const float* __restrict__ cw1, const float* __restrict__ cb1,
        const float* __restrict__ cw2, const float* __restrict__ cb2,
        const float* __restrict__ lnw, const float* __restrict__ lnb) {
    __shared__ float s_w1t[64 * 68];
    __shared__ float s_w2t[64 * 68];
    __shared__ float s_b1[64], s_b2[64], s_g[64], s_bt[64];
    __shared__ float s_m[4][64];
    int tid = threadIdx.x;
    for (int i = tid; i < 4096; i += 256) {
        int kk = i >> 6, k = i & 63;
        s_w1t[k * 68 + kk] = cw1[i];
        s_w2t[k * 68 + kk] = cw2[i];
    }
    if (tid < 64) { s_b1[tid] = cb1[tid]; s_g[tid] = lnw[tid]; }
    else if (tid < 128) { s_b2[tid - 64] = cb2[tid - 64]; s_bt[tid - 64] = lnb[tid - 64]; }
    __syncthreads();

    int w = tid >> 6, k = tid & 63;
    #pragma unroll
    for (int nn = 0; nn < 4; ++nn) {
        int n = blockIdx.x * 16 + w * 4 + nn;
        float m = toF(M[(size_t)n * 64 + k]);
        s_m[w][k] = m;                       // wave-private LDS exchange
        __builtin_amdgcn_wave_barrier();
        float acc = s_b1[k];
        {
            const float4* wr = (const float4*)&s_w1t[k * 68];
            const float4* mr = (const float4*)&s_m[w][0];
            #pragma unroll
            for (int q = 0; q < 16; ++q) {
                float4 wv = wr[q], mv = mr[q];
                acc += mv.x * wv.x + mv.y * wv.y + mv.z * wv.z + mv.w * wv.w;
            }
        }
        float u = fmaxf(acc, 0.f);
        __builtin_amdgcn_wave_barrier();
        s_m[w][k] = u;
        __builtin_amdgcn_wave_barrier();
        float acc2 = s_b2[k];
        {
            const float4* wr = (const float4*)&s_w2t[k * 68];
            const float4* mr = (const float4*)&s_m[w][0];
            #pragma unroll
            for (int q = 0; q < 16; ++q) {
                float4 wv = wr[q], mv = mr[q];
                acc2 += mv.x * wv.x + mv.y * wv.y + mv.z * wv.z + mv.w * wv.w;
            }
        }
        float v = acc2;
        float sum = v, sq = v * v;
        #pragma unroll
        for (int off = 32; off > 0; off >>= 1) {
            sum += __shfl_xor(sum, off, 64);
            sq  += __shfl_xor(sq, off, 64);
        }
        float mu  = sum * (1.f / 64.f);
        float var = sq * (1.f / 64.f) - mu * mu;
        float y = (v - mu) * rsqrtf(var + 1e-5f) * s_g[k] + s_bt[k];
        float ge = 0.5f * y * (1.f + erff(y * 0.70710678118654752f));
        float identity = A[(size_t)n * 64 + k];
        A[(size_t)n * 64 + k] = ge + identity;   // node-local: race-free in-place
    }
}

// ---------- final: out = LN(h@(fw+rw) + (fb+rb); ow, ob) ----------
__global__ __launch_bounds__(256) void k_final(const float* __restrict__ h,
        const float* __restrict__ fw, const float* __restrict__ fb,
        const float* __restrict__ rw, const float* __restrict__ rb,
        const float* __restrict__ ow, const float* __restrict__ ob,
        float* __restrict__ out) {
    __shared__ float s_wT[128 * 68];   // [c][k], combined fw+rw
    __shared__ float s_b[128];
    __shared__ float s_h[2][64];
    __shared__ float s_red[4][2];
    int tid = threadIdx.x;
    for (int i = tid; i < 8192; i += 256) {
        int k = i >> 7, c = i & 127;
        s_wT[c * 68 + k] = fw[i] + rw[i];
    }
    if (tid < 128) s_b[tid] = fb[tid] + rb[tid];
    int half = tid >> 7, c = tid & 127;
    int n = blockIdx.x * 2 + half;
    if (c < 64) s_h[half][c] = h[(size_t)n * 64 + c];
    __syncthreads();

    float acc = s_b[c];
    const float4* wr = (const float4*)&s_wT[c * 68];
    const float4* hr = (const float4*)&s_h[half][0];
    #pragma unroll
    for (int q = 0; q < 16; ++q) {
        float4 wv = wr[q], hv = hr[q];
        acc += hv.x * wv.x + hv.y * wv.y + hv.z * wv.z + hv.w * wv.w;
    }
    float v = acc;
    float sum = v, sq = v * v;
    #pragma unroll
    for (int off = 32; off > 0; off >>= 1) {
        sum += __shfl_xor(sum, off, 64);
        sq  += __shfl_xor(sq, off, 64);
    }
    int wid = tid >> 6;
    if ((tid & 63) == 0) { s_red[wid][0] = sum; s_red[wid][1] = sq; }
    __syncthreads();
    float tsum = s_red[half * 2][0] + s_red[half * 2 + 1][0];
    float tsq  = s_red[half * 2][1] + s_red[half * 2 + 1][1];
    float mu  = tsum * (1.f / 128.f);
    float var = tsq * (1.f / 128.f) - mu * mu;
    float y = (v - mu) * rsqrtf(var + 1e-5f) * ow[c] + ob[c];
    out[(size_t)n * 128 + c] = y;
}

extern "C" void kernel_launch(void* const* d_in, const int* in_sizes, int n_in,
                              void* d_out, int out_size, void* d_ws, size_t ws_size,
                              hipStream_t stream) {
    const float* x    = (const float*)d_in[0];
    const int*   ei   = (const int*)d_in[1];
    const float* in_w = (const float*)d_in[2];
    const float* in_b = (const float*)d_in[3];
    const float* ew1  = (const float*)d_in[4];
    const float* eb1  = (const float*)d_in[5];
    const float* ew2  = (const float*)d_in[6];
    const float* eb2  = (const float*)d_in[7];
    const float* cw1  = (const float*)d_in[8];
    const float* cb1  = (const float*)d_in[9];
    const float* cw2  = (const float*)d_in[10];
    const float* cb2  = (const float*)d_in[11];
    const float* lnw  = (const float*)d_in[12];
    const float* lnb  = (const float*)d_in[13];
    const float* fw   = (const float*)d_in[14];
    const float* fb   = (const float*)d_in[15];
    const float* rw   = (const float*)d_in[16];
    const float* rb   = (const float*)d_in[17];
    const float* ow   = (const float*)d_in[18];
    const float* ob   = (const float*)d_in[19];
    float* out = (float*)d_out;

    // workspace layout (bytes):
    //   ea     : NE*64*2            = 102,400,000     @ 0
    //   A (h)  : NN*64*4            =  12,800,000     @ 102,400,000
    //   rows   : NE*2 (u16)         =   1,600,000     @ 115,200,000
    //   offcur : (NN+1)*4 (+pad)    =     200,016     @ 116,800,000
    //   M      : NN*64*{4|2}        =  12.8M | 6.4M   @ 117,000,016
    //   dpos   : NE*4 = 3.2M  (aliases M region; dead before layer 0)
    char* ws = (char*)d_ws;
    unsigned short* ea   = (unsigned short*)ws;
    float*          A    = (float*)(ws + 102400000);
    unsigned short* rows = (unsigned short*)(ws + 115200000);
    int*            off  = (int*)(ws + 116800000);
    char*           Mp   = ws + 117000016;
    int*            dpos = (int*)Mp;

    const bool m32 = (ws_size >= 129800016ull);   // fp32 M fits?

    hipMemsetAsync(off, 0, (NN + 1) * sizeof(int), stream);
    k_deg<<<NE / 256, 256, 0, stream>>>(ei, off);
    k_scan<<<1, 1024, 0, stream>>>(off);
    k_scatter<<<NE / 256, 256, 0, stream>>>(ei, off, rows, dpos);
    k_input<<<NN / 4, 256, 0, stream>>>(x, in_w, in_b, A);
    k_edge<<<NE / 64, 256, 0, stream>>>(x, ei, ew1, eb1, ew2, eb2, dpos, ea);

    for (int l = 0; l < 4; ++l) {
        const float* w1 = cw1 + (size_t)l * 4096;
        const float* b1 = cb1 + (size_t)l * 64;
        const float* w2 = cw2 + (size_t)l * 4096;
        const float* b2 = cb2 + (size_t)l * 64;
        const float* g  = lnw + (size_t)l * 64;
        const float* bt = lnb + (size_t)l * 64;
        if (m32) {
            k_agg<float><<<NN / 4, 256, 0, stream>>>(A, ea, rows, off, (float*)Mp);
            k_node<float><<<NN / 16, 256, 0, stream>>>(A, (const float*)Mp, w1, b1, w2, b2, g, bt);
        } else {
            k_agg<__half><<<NN / 4, 256, 0, stream>>>(A, ea, rows, off, (__half*)Mp);
            k_node<__half><<<NN / 16, 256, 0, stream>>>(A, (const __half*)Mp, w1, b1, w2, b2, g, bt);
        }
    }
    k_final<<<NN / 2, 256, 0, stream>>>(A, fw, fb, rw, rb, ow, ob, out);
}

// Round 3
// 699.035 us; speedup vs baseline: 4.7331x; 1.2405x over previous
//
#include <hip/hip_runtime.h>
#include <hip/hip_fp16.h>
#include <stdint.h>

#define NN 50000
#define NE 800000

static __device__ __forceinline__ unsigned short f2bf(float f) {
    unsigned int u = __float_as_uint(f);
    u += 0x7fffu + ((u >> 16) & 1u);   // round-to-nearest-even
    return (unsigned short)(u >> 16);
}
static __device__ __forceinline__ float bf2f(unsigned short s) {
    return __uint_as_float(((unsigned int)s) << 16);
}
static __device__ __forceinline__ float toF(float v) { return v; }
static __device__ __forceinline__ float toF(__half v) { return __half2float(v); }
static __device__ __forceinline__ void fromF(float& d, float v) { d = v; }
static __device__ __forceinline__ void fromF(__half& d, float v) { d = __float2half(v); }

static __device__ __forceinline__ float4 fma4(float4 a, float s, float4 w) {
    a.x = fmaf(s, w.x, a.x); a.y = fmaf(s, w.y, a.y);
    a.z = fmaf(s, w.z, a.z); a.w = fmaf(s, w.w, a.w);
    return a;
}

// ---------- CSR build ----------
__global__ __launch_bounds__(256) void k_deg(const int* __restrict__ ei, int* __restrict__ offcur) {
    int e = blockIdx.x * 256 + threadIdx.x;
    atomicAdd(&offcur[ei[NE + e]], 1);
}

__global__ __launch_bounds__(1024) void k_scan(int* __restrict__ offcur) {
    __shared__ int s[1024];
    const int C = (NN + 1023) / 1024;   // 49
    int t = threadIdx.x;
    int base = t * C;
    int sum = 0;
    for (int i = 0; i < C; ++i) { int idx = base + i; if (idx < NN) sum += offcur[idx]; }
    s[t] = sum; __syncthreads();
    for (int d = 1; d < 1024; d <<= 1) {
        int v = (t >= d) ? s[t - d] : 0;
        __syncthreads();
        s[t] += v;
        __syncthreads();
    }
    int run = (t > 0) ? s[t - 1] : 0;
    for (int i = 0; i < C; ++i) {
        int idx = base + i;
        if (idx < NN) { int d = offcur[idx]; offcur[idx] = run; run += d; }
    }
    if (t == 1023) offcur[NN] = s[1023];
}

__global__ __launch_bounds__(256) void k_scatter(const int* __restrict__ ei,
        int* __restrict__ offcur, unsigned short* __restrict__ rows, int* __restrict__ dpos) {
    int e = blockIdx.x * 256 + threadIdx.x;
    int col = ei[NE + e];
    int pos = atomicAdd(&offcur[col], 1);
    rows[pos] = (unsigned short)ei[e];
    dpos[e] = pos;
}

// ---------- h init ----------
__global__ __launch_bounds__(256) void k_input(const float* __restrict__ x,
        const float* __restrict__ in_w, const float* __restrict__ in_b,
        float* __restrict__ h) {
    int n = blockIdx.x * 4 + (threadIdx.x >> 6);
    int k = threadIdx.x & 63;
    const float* xr = x + (size_t)n * 3;
    h[(size_t)n * 64 + k] = in_b[k] + xr[0] * in_w[k] + xr[1] * in_w[64 + k] + xr[2] * in_w[128 + k];
}

// ---------- edge MLP -> ea (bf16), written in dest-sorted order ----------
__global__ __launch_bounds__(256) void k_edge(const float* __restrict__ x,
        const int* __restrict__ ei,
        const float* __restrict__ ew1, const float* __restrict__ eb1,
        const float* __restrict__ ew2, const float* __restrict__ eb2,
        const int* __restrict__ dpos, unsigned short* __restrict__ ea) {
    __shared__ float s_w2[64 * 64];
    __shared__ float s_tT[64 * 64];   // [j][edge]
    __shared__ float s_w1[128];
    __shared__ float s_b1[64];
    __shared__ float s_b2[64];
    int tid = threadIdx.x;
    for (int i = tid; i < 4096; i += 256) s_w2[i] = ew2[i];
    if (tid < 128) s_w1[tid] = ew1[tid];
    if (tid < 64) s_b1[tid] = eb1[tid];
    else if (tid < 128) s_b2[tid - 64] = eb2[tid - 64];
    __syncthreads();

    int e0 = blockIdx.x * 64;
    int et = tid & 63;
    int jb = tid >> 6;
    int e = e0 + et;
    int r = ei[e], c = ei[NE + e];
    float rx = x[(size_t)c * 3]     - x[(size_t)r * 3];
    float ry = x[(size_t)c * 3 + 1] - x[(size_t)r * 3 + 1];
    #pragma unroll
    for (int jj = 0; jj < 16; ++jj) {
        int j = jb * 16 + jj;
        float t = fmaxf(rx * s_w1[j] + ry * s_w1[64 + j] + s_b1[j], 0.f);
        s_tT[j * 64 + et] = t;
    }
    __syncthreads();

    int er = (tid >> 4) << 2;
    int cc = (tid & 15) << 2;
    float4 acc0 = {0,0,0,0}, acc1 = {0,0,0,0}, acc2 = {0,0,0,0}, acc3 = {0,0,0,0};
    #pragma unroll 8
    for (int k = 0; k < 64; ++k) {
        float4 w = *(const float4*)&s_w2[k * 64 + cc];
        float4 t = *(const float4*)&s_tT[k * 64 + er];
        acc0.x += t.x * w.x; acc0.y += t.x * w.y; acc0.z += t.x * w.z; acc0.w += t.x * w.w;
        acc1.x += t.y * w.x; acc1.y += t.y * w.y; acc1.z += t.y * w.z; acc1.w += t.y * w.w;
        acc2.x += t.z * w.x; acc2.y += t.z * w.y; acc2.z += t.z * w.z; acc2.w += t.z * w.w;
        acc3.x += t.w * w.x; acc3.y += t.w * w.y; acc3.z += t.w * w.z; acc3.w += t.w * w.w;
    }
    float4 b2 = *(const float4*)&s_b2[cc];
    float4 accs[4] = {acc0, acc1, acc2, acc3};
    #pragma unroll
    for (int i = 0; i < 4; ++i) {
        int pos = dpos[e0 + er + i];
        ushort4 o;
        o.x = f2bf(accs[i].x + b2.x);
        o.y = f2bf(accs[i].y + b2.y);
        o.z = f2bf(accs[i].z + b2.z);
        o.w = f2bf(accs[i].w + b2.w);
        *(ushort4*)&ea[(size_t)pos * 64 + cc] = o;
    }
}

// ---------- per-layer: gather aggregate (atomic-free) ----------
template <typename MT>
__global__ __launch_bounds__(256) void k_agg(const float* __restrict__ A,
        const unsigned short* __restrict__ ea, const unsigned short* __restrict__ rows,
        const int* __restrict__ offcur, MT* __restrict__ M) {
    int w = threadIdx.x >> 6, k = threadIdx.x & 63;
    int n = blockIdx.x * 4 + w;
    int p0 = (n == 0) ? 0 : offcur[n - 1];
    int p1 = offcur[n];
    float acc0 = A[(size_t)n * 64 + k];
    float acc1 = 0.f;
    for (int base = p0; base < p1; base += 64) {
        int cnt = min(64, p1 - base);
        int rl = (k < cnt) ? (int)rows[base + k] : 0;
        int j = 0;
        for (; j + 2 <= cnt; j += 2) {
            int r0 = __shfl(rl, j, 64);
            int r1 = __shfl(rl, j + 1, 64);
            float h0 = A[(size_t)r0 * 64 + k];
            float h1 = A[(size_t)r1 * 64 + k];
            float e0 = bf2f(ea[(size_t)(base + j) * 64 + k]);
            float e1 = bf2f(ea[(size_t)(base + j + 1) * 64 + k]);
            acc0 += fmaxf(h0 + e0, 0.f);
            acc1 += fmaxf(h1 + e1, 0.f);
        }
        if (j < cnt) {
            int r0 = __shfl(rl, j, 64);
            acc0 += fmaxf(A[(size_t)r0 * 64 + k] + bf2f(ea[(size_t)(base + j) * 64 + k]), 0.f);
        }
    }
    fromF(M[(size_t)n * 64 + k], acc0 + acc1);
}

// ---------- per-layer: node MLP + LN + gelu + residual ----------
// rank-1 register-tiled: 64 nodes/block, wave = 16 nodes x 64 ch,
// lane = (cq = channel quad, ng = node group of 4). Conflict-free LDS.
template <typename MT>
__global__ __launch_bounds__(256) void k_node(float* __restrict__ A, const MT* __restrict__ M,
        const float* __restrict__ cw1, const float* __restrict__ cb1,
        const float* __restrict__ cw2, const float* __restrict__ cb2,
        const float* __restrict__ lnw, const float* __restrict__ lnb) {
    __shared__ float s_W1[64 * 64];     // [k][c] row-major
    __shared__ float s_W2[64 * 64];
    __shared__ float s_m[64 * 68];      // [node][k], stride 68 (16B aligned, bank-spread)
    __shared__ float s_b1[64], s_b2[64], s_g[64], s_bt[64];
    int tid = threadIdx.x;
    for (int i = tid; i < 4096; i += 256) { s_W1[i] = cw1[i]; s_W2[i] = cw2[i]; }
    if (tid < 64) { s_b1[tid] = cb1[tid]; s_g[tid] = lnw[tid]; }
    else if (tid < 128) { s_b2[tid - 64] = cb2[tid - 64]; s_bt[tid - 64] = lnb[tid - 64]; }
    int nb = blockIdx.x * 64;
    for (int i = tid; i < 4096; i += 256) {
        int nl = i >> 6, k = i & 63;
        int n = nb + nl;
        s_m[nl * 68 + k] = (n < NN) ? toF(M[(size_t)n * 64 + k]) : 0.f;
    }
    __syncthreads();

    int lane = tid & 63, w = tid >> 6;
    int cq = lane & 15, ng = lane >> 4;
    int rbase = w * 16 + ng * 4;        // this lane's 4 node rows in s_m
    int c0 = cq * 4;

    // ---- matmul1: u = relu(m @ W1 + b1) ----
    float4 acc[4];
    {
        float4 b1q = *(const float4*)&s_b1[c0];
        acc[0] = b1q; acc[1] = b1q; acc[2] = b1q; acc[3] = b1q;
    }
    #pragma unroll 8
    for (int k = 0; k < 64; ++k) {
        float4 w4 = *(const float4*)&s_W1[k * 64 + c0];
        float m0 = s_m[(rbase + 0) * 68 + k];
        float m1 = s_m[(rbase + 1) * 68 + k];
        float m2 = s_m[(rbase + 2) * 68 + k];
        float m3 = s_m[(rbase + 3) * 68 + k];
        acc[0] = fma4(acc[0], m0, w4);
        acc[1] = fma4(acc[1], m1, w4);
        acc[2] = fma4(acc[2], m2, w4);
        acc[3] = fma4(acc[3], m3, w4);
    }
    __builtin_amdgcn_wave_barrier();
    #pragma unroll
    for (int j = 0; j < 4; ++j) {
        float4 u;
        u.x = fmaxf(acc[j].x, 0.f); u.y = fmaxf(acc[j].y, 0.f);
        u.z = fmaxf(acc[j].z, 0.f); u.w = fmaxf(acc[j].w, 0.f);
        *(float4*)&s_m[(rbase + j) * 68 + c0] = u;   // own rows only: wave-local
    }
    __builtin_amdgcn_wave_barrier();

    // ---- matmul2: v = u @ W2 + b2 ----
    {
        float4 b2q = *(const float4*)&s_b2[c0];
        acc[0] = b2q; acc[1] = b2q; acc[2] = b2q; acc[3] = b2q;
    }
    #pragma unroll 8
    for (int k = 0; k < 64; ++k) {
        float4 w4 = *(const float4*)&s_W2[k * 64 + c0];
        float m0 = s_m[(rbase + 0) * 68 + k];
        float m1 = s_m[(rbase + 1) * 68 + k];
        float m2 = s_m[(rbase + 2) * 68 + k];
        float m3 = s_m[(rbase + 3) * 68 + k];
        acc[0] = fma4(acc[0], m0, w4);
        acc[1] = fma4(acc[1], m1, w4);
        acc[2] = fma4(acc[2], m2, w4);
        acc[3] = fma4(acc[3], m3, w4);
    }

    // ---- LN (64 ch, within 16-lane cq group) + gelu + residual ----
    float4 gq  = *(const float4*)&s_g[c0];
    float4 btq = *(const float4*)&s_bt[c0];
    #pragma unroll
    for (int j = 0; j < 4; ++j) {
        float4 v = acc[j];
        float sum = v.x + v.y + v.z + v.w;
        float sq  = v.x * v.x + v.y * v.y + v.z * v.z + v.w * v.w;
        #pragma unroll
        for (int m = 1; m < 16; m <<= 1) {
            sum += __shfl_xor(sum, m, 64);
            sq  += __shfl_xor(sq, m, 64);
        }
        float mu  = sum * (1.f / 64.f);
        float var = sq * (1.f / 64.f) - mu * mu;
        float rs  = rsqrtf(var + 1e-5f);
        int n = nb + rbase + j;
        if (n < NN) {
            float4 id = *(const float4*)&A[(size_t)n * 64 + c0];
            float4 o;
            float y;
            y = (v.x - mu) * rs * gq.x + btq.x; o.x = 0.5f * y * (1.f + erff(y * 0.70710678118654752f)) + id.x;
            y = (v.y - mu) * rs * gq.y + btq.y; o.y = 0.5f * y * (1.f + erff(y * 0.70710678118654752f)) + id.y;
            y = (v.z - mu) * rs * gq.z + btq.z; o.z = 0.5f * y * (1.f + erff(y * 0.70710678118654752f)) + id.z;
            y = (v.w - mu) * rs * gq.w + btq.w; o.w = 0.5f * y * (1.f + erff(y * 0.70710678118654752f)) + id.w;
            *(float4*)&A[(size_t)n * 64 + c0] = o;
        }
    }
}

// ---------- final: out = LN(h@(fw+rw) + (fb+rb); ow, ob) ----------
// 32 nodes/block; wave = 16 nodes x 64-ch half; conflict-free rank-1 form.
__global__ __launch_bounds__(256) void k_final(const float* __restrict__ h,
        const float* __restrict__ fw, const float* __restrict__ fb,
        const float* __restrict__ rw, const float* __restrict__ rb,
        const float* __restrict__ ow, const float* __restrict__ ob,
        float* __restrict__ out) {
    __shared__ float s_W[64 * 128];     // [k][c] row-major, combined fw+rw
    __shared__ float s_h[32 * 68];
    __shared__ float s_b[128];
    __shared__ float s_red[32][4];      // sum0, sq0, sum1, sq1
    int tid = threadIdx.x;
    for (int i = tid; i < 8192; i += 256) s_W[i] = fw[i] + rw[i];
    if (tid < 128) s_b[tid] = fb[tid] + rb[tid];
    int nb = blockIdx.x * 32;
    for (int i = tid; i < 2048; i += 256) {
        int nl = i >> 6, k = i & 63;
        int n = nb + nl;
        s_h[nl * 68 + k] = (n < NN) ? h[(size_t)n * 64 + k] : 0.f;
    }
    __syncthreads();

    int lane = tid & 63, w = tid >> 6;
    int chh = w & 1, nh = w >> 1;       // channel half, node half
    int cq = lane & 15, ng = lane >> 4;
    int c0 = chh * 64 + cq * 4;
    int rbase = nh * 16 + ng * 4;

    float4 acc[4];
    {
        float4 bq = *(const float4*)&s_b[c0];
        acc[0] = bq; acc[1] = bq; acc[2] = bq; acc[3] = bq;
    }
    #pragma unroll 8
    for (int k = 0; k < 64; ++k) {
        float4 w4 = *(const float4*)&s_W[k * 128 + c0];
        float m0 = s_h[(rbase + 0) * 68 + k];
        float m1 = s_h[(rbase + 1) * 68 + k];
        float m2 = s_h[(rbase + 2) * 68 + k];
        float m3 = s_h[(rbase + 3) * 68 + k];
        acc[0] = fma4(acc[0], m0, w4);
        acc[1] = fma4(acc[1], m1, w4);
        acc[2] = fma4(acc[2], m2, w4);
        acc[3] = fma4(acc[3], m3, w4);
    }
    #pragma unroll
    for (int j = 0; j < 4; ++j) {
        float4 v = acc[j];
        float sum = v.x + v.y + v.z + v.w;
        float sq  = v.x * v.x + v.y * v.y + v.z * v.z + v.w * v.w;
        #pragma unroll
        for (int m = 1; m < 16; m <<= 1) {
            sum += __shfl_xor(sum, m, 64);
            sq  += __shfl_xor(sq, m, 64);
        }
        if (cq == 0) {
            s_red[rbase + j][chh * 2]     = sum;
            s_red[rbase + j][chh * 2 + 1] = sq;
        }
    }
    __syncthreads();
    float4 gq = *(const float4*)&ow[c0];
    float4 bq = *(const float4*)&ob[c0];
    #pragma unroll
    for (int j = 0; j < 4; ++j) {
        int nl = rbase + j;
        int n = nb + nl;
        float tsum = s_red[nl][0] + s_red[nl][2];
        float tsq  = s_red[nl][1] + s_red[nl][3];
        float mu  = tsum * (1.f / 128.f);
        float var = tsq * (1.f / 128.f) - mu * mu;
        float rs  = rsqrtf(var + 1e-5f);
        if (n < NN) {
            float4 v = acc[j];
            float4 o;
            o.x = (v.x - mu) * rs * gq.x + bq.x;
            o.y = (v.y - mu) * rs * gq.y + bq.y;
            o.z = (v.z - mu) * rs * gq.z + bq.z;
            o.w = (v.w - mu) * rs * gq.w + bq.w;
            *(float4*)&out[(size_t)n * 128 + c0] = o;
        }
    }
}

extern "C" void kernel_launch(void* const* d_in, const int* in_sizes, int n_in,
                              void* d_out, int out_size, void* d_ws, size_t ws_size,
                              hipStream_t stream) {
    const float* x    = (const float*)d_in[0];
    const int*   ei   = (const int*)d_in[1];
    const float* in_w = (const float*)d_in[2];
    const float* in_b = (const float*)d_in[3];
    const float* ew1  = (const float*)d_in[4];
    const float* eb1  = (const float*)d_in[5];
    const float* ew2  = (const float*)d_in[6];
    const float* eb2  = (const float*)d_in[7];
    const float* cw1  = (const float*)d_in[8];
    const float* cb1  = (const float*)d_in[9];
    const float* cw2  = (const float*)d_in[10];
    const float* cb2  = (const float*)d_in[11];
    const float* lnw  = (const float*)d_in[12];
    const float* lnb  = (const float*)d_in[13];
    const float* fw   = (const float*)d_in[14];
    const float* fb   = (const float*)d_in[15];
    const float* rw   = (const float*)d_in[16];
    const float* rb   = (const float*)d_in[17];
    const float* ow   = (const float*)d_in[18];
    const float* ob   = (const float*)d_in[19];
    float* out = (float*)d_out;

    // workspace layout (bytes):
    //   ea     : NE*64*2            = 102,400,000     @ 0
    //   A (h)  : NN*64*4            =  12,800,000     @ 102,400,000
    //   rows   : NE*2 (u16)         =   1,600,000     @ 115,200,000
    //   offcur : (NN+1)*4 (+pad)    =     200,016     @ 116,800,000
    //   M      : NN*64*{4|2}        =  12.8M | 6.4M   @ 117,000,016
    //   dpos   : NE*4 = 3.2M  (aliases M region; dead before layer 0)
    char* ws = (char*)d_ws;
    unsigned short* ea   = (unsigned short*)ws;
    float*          A    = (float*)(ws + 102400000);
    unsigned short* rows = (unsigned short*)(ws + 115200000);
    int*            off  = (int*)(ws + 116800000);
    char*           Mp   = ws + 117000016;
    int*            dpos = (int*)Mp;

    const bool m32 = (ws_size >= 129800016ull);

    hipMemsetAsync(off, 0, (NN + 1) * sizeof(int), stream);
    k_deg<<<NE / 256, 256, 0, stream>>>(ei, off);
    k_scan<<<1, 1024, 0, stream>>>(off);
    k_scatter<<<NE / 256, 256, 0, stream>>>(ei, off, rows, dpos);
    k_input<<<NN / 4, 256, 0, stream>>>(x, in_w, in_b, A);
    k_edge<<<NE / 64, 256, 0, stream>>>(x, ei, ew1, eb1, ew2, eb2, dpos, ea);

    const int nodeBlocks = (NN + 63) / 64;     // 782
    for (int l = 0; l < 4; ++l) {
        const float* w1 = cw1 + (size_t)l * 4096;
        const float* b1 = cb1 + (size_t)l * 64;
        const float* w2 = cw2 + (size_t)l * 4096;
        const float* b2 = cb2 + (size_t)l * 64;
        const float* g  = lnw + (size_t)l * 64;
        const float* bt = lnb + (size_t)l * 64;
        if (m32) {
            k_agg<float><<<NN / 4, 256, 0, stream>>>(A, ea, rows, off, (float*)Mp);
            k_node<float><<<nodeBlocks, 256, 0, stream>>>(A, (const float*)Mp, w1, b1, w2, b2, g, bt);
        } else {
            k_agg<__half><<<NN / 4, 256, 0, stream>>>(A, ea, rows, off, (__half*)Mp);
            k_node<__half><<<nodeBlocks, 256, 0, stream>>>(A, (const __half*)Mp, w1, b1, w2, b2, g, bt);
        }
    }
    k_final<<<(NN + 31) / 32, 256, 0, stream>>>(A, fw, fb, rw, rb, ow, ob, out);
}

// Round 4
// 655.517 us; speedup vs baseline: 5.0473x; 1.0664x over previous
//
#include <hip/hip_runtime.h>
#include <hip/hip_fp16.h>
#include <stdint.h>

#define NN 50000
#define NE 800000

typedef short short8 __attribute__((ext_vector_type(8)));
typedef float f32x4 __attribute__((ext_vector_type(4)));

static __device__ __forceinline__ unsigned short f2bf(float f) {
    unsigned int u = __float_as_uint(f);
    u += 0x7fffu + ((u >> 16) & 1u);   // round-to-nearest-even
    return (unsigned short)(u >> 16);
}
static __device__ __forceinline__ float bf2f(unsigned short s) {
    return __uint_as_float(((unsigned int)s) << 16);
}
static __device__ __forceinline__ float toF(float v) { return v; }
static __device__ __forceinline__ float toF(__half v) { return __half2float(v); }
static __device__ __forceinline__ void st2(float* p, float x, float y) {
    *(float2*)p = make_float2(x, y);
}
static __device__ __forceinline__ void st2(__half* p, float x, float y) {
    __half2 h; h.x = __float2half(x); h.y = __float2half(y);
    *(__half2*)p = h;
}

static __device__ __forceinline__ float4 fma4(float4 a, float s, float4 w) {
    a.x = fmaf(s, w.x, a.x); a.y = fmaf(s, w.y, a.y);
    a.z = fmaf(s, w.z, a.z); a.w = fmaf(s, w.w, a.w);
    return a;
}

// ---------- CSR build ----------
__global__ __launch_bounds__(256) void k_deg(const int* __restrict__ ei, int* __restrict__ offcur) {
    int e = blockIdx.x * 256 + threadIdx.x;
    atomicAdd(&offcur[ei[NE + e]], 1);
}

__global__ __launch_bounds__(1024) void k_scan(int* __restrict__ offcur) {
    __shared__ int s[1024];
    const int C = (NN + 1023) / 1024;   // 49
    int t = threadIdx.x;
    int base = t * C;
    int sum = 0;
    for (int i = 0; i < C; ++i) { int idx = base + i; if (idx < NN) sum += offcur[idx]; }
    s[t] = sum; __syncthreads();
    for (int d = 1; d < 1024; d <<= 1) {
        int v = (t >= d) ? s[t - d] : 0;
        __syncthreads();
        s[t] += v;
        __syncthreads();
    }
    int run = (t > 0) ? s[t - 1] : 0;
    for (int i = 0; i < C; ++i) {
        int idx = base + i;
        if (idx < NN) { int d = offcur[idx]; offcur[idx] = run; run += d; }
    }
    if (t == 1023) offcur[NN] = s[1023];
}

__global__ __launch_bounds__(256) void k_scatter(const int* __restrict__ ei,
        int* __restrict__ offcur, unsigned short* __restrict__ rows, int* __restrict__ dpos) {
    int e = blockIdx.x * 256 + threadIdx.x;
    int col = ei[NE + e];
    int pos = atomicAdd(&offcur[col], 1);
    rows[pos] = (unsigned short)ei[e];
    dpos[e] = pos;
}

// ---------- h init ----------
__global__ __launch_bounds__(256) void k_input(const float* __restrict__ x,
        const float* __restrict__ in_w, const float* __restrict__ in_b,
        float* __restrict__ h) {
    int n = blockIdx.x * 4 + (threadIdx.x >> 6);
    int k = threadIdx.x & 63;
    const float* xr = x + (size_t)n * 3;
    h[(size_t)n * 64 + k] = in_b[k] + xr[0] * in_w[k] + xr[1] * in_w[64 + k] + xr[2] * in_w[128 + k];
}

// ---------- edge MLP -> ea (bf16) via MFMA, written in dest-sorted order ----------
// block = 64 edges; t (64x64) and w2 staged bf16 in LDS; 16x16x32 bf16 MFMA.
__global__ __launch_bounds__(256) void k_edge(const float* __restrict__ x,
        const int* __restrict__ ei,
        const float* __restrict__ ew1, const float* __restrict__ eb1,
        const float* __restrict__ ew2, const float* __restrict__ eb2,
        const int* __restrict__ dpos, unsigned short* __restrict__ ea) {
    __shared__ unsigned short s_w2f[8][64][8];   // [kt*4+nt][lane][j]  (B-frags)
    __shared__ unsigned short s_t[64][72];       // t, [edge][k] padded
    __shared__ unsigned short s_d[64][72];       // D staging, [edge][c] padded
    __shared__ float s_w1[128], s_b1[64], s_b2[64];
    int tid = threadIdx.x;

    // stage w2 as bf16 B-fragments: B[k][n], lane = (k_in/8)*16 + (n&15), j = k&7
    for (int i = tid; i < 4096; i += 256) {
        int k = i >> 6, n = i & 63;
        int kt = k >> 5, kin = k & 31;
        int quad = kin >> 3, j = kin & 7;
        int nt = n >> 4, nin = n & 15;
        s_w2f[kt * 4 + nt][quad * 16 + nin][j] = f2bf(ew2[i]);
    }
    if (tid < 128) s_w1[tid] = ew1[tid];
    if (tid < 64) s_b1[tid] = eb1[tid];
    else if (tid < 128) s_b2[tid - 64] = eb2[tid - 64];

    // compute t = relu(rel_pos @ w1 + b1) into LDS (bf16)
    int eb = blockIdx.x * 64;
    int et = tid & 63;
    int jb = tid >> 6;
    {
        int e = eb + et;
        int r = ei[e], c = ei[NE + e];
        float rx = x[(size_t)c * 3]     - x[(size_t)r * 3];
        float ry = x[(size_t)c * 3 + 1] - x[(size_t)r * 3 + 1];
        __syncthreads();   // s_w1/s_b1 ready
        #pragma unroll
        for (int jj = 0; jj < 16; ++jj) {
            int j = jb * 16 + jj;
            float t = fmaxf(rx * s_w1[j] + ry * s_w1[64 + j] + s_b1[j], 0.f);
            s_t[et][j] = f2bf(t);
        }
    }
    __syncthreads();

    // MFMA: wave w -> edge rows w*16..w*16+15, all 64 out channels
    int w = tid >> 6, lane = tid & 63;
    int lm = lane & 15, lq = lane >> 4;
    f32x4 acc[4];
    #pragma unroll
    for (int nt = 0; nt < 4; ++nt) {
        float b = s_b2[nt * 16 + lm];
        acc[nt][0] = b; acc[nt][1] = b; acc[nt][2] = b; acc[nt][3] = b;
    }
    #pragma unroll
    for (int kt = 0; kt < 2; ++kt) {
        short8 a = *(const short8*)&s_t[w * 16 + lm][kt * 32 + lq * 8];
        #pragma unroll
        for (int nt = 0; nt < 4; ++nt) {
            short8 b = *(const short8*)&s_w2f[kt * 4 + nt][lane][0];
            acc[nt] = __builtin_amdgcn_mfma_f32_16x16x32_bf16(a, b, acc[nt], 0, 0, 0);
        }
    }

    // epilogue: D -> bf16 LDS staging (C/D layout: col=lane&15, row=(lane>>4)*4+reg)
    #pragma unroll
    for (int nt = 0; nt < 4; ++nt) {
        #pragma unroll
        for (int r = 0; r < 4; ++r) {
            int row = w * 16 + lq * 4 + r;
            s_d[row][nt * 16 + lm] = f2bf(acc[nt][r]);
        }
    }
    __syncthreads();

    // coalesced scatter-store: 4 threads/row, 32 B each
    int row = tid >> 2, seg = tid & 3;
    int pos = dpos[eb + row];
    uint4 v0 = *(const uint4*)&s_d[row][seg * 16];
    uint4 v1 = *(const uint4*)&s_d[row][seg * 16 + 8];
    uint4* dst = (uint4*)&ea[(size_t)pos * 64 + seg * 16];
    dst[0] = v0;
    dst[1] = v1;
}

// ---------- per-layer: gather aggregate (atomic-free) ----------
// wave per node; lane = (edge sublane e_sub = lane>>5) x (channel pair ch2 = lane&31)
// 4 edges per iteration, independent vector loads.
template <typename MT>
__global__ __launch_bounds__(256) void k_agg(const float* __restrict__ A,
        const unsigned short* __restrict__ ea, const unsigned short* __restrict__ rows,
        const int* __restrict__ offcur, MT* __restrict__ M) {
    const float2* A2 = (const float2*)A;
    const unsigned int* EA = (const unsigned int*)ea;
    int w = threadIdx.x >> 6, lane = threadIdx.x & 63;
    int es = lane >> 5, ch2 = lane & 31;
    int n = blockIdx.x * 4 + w;
    int p0 = (n == 0) ? 0 : offcur[n - 1];
    int p1 = offcur[n];
    float ax0 = 0.f, ay0 = 0.f, ax1 = 0.f, ay1 = 0.f;
    for (int base = p0; base < p1; base += 64) {
        int cnt = min(64, p1 - base);
        int rl = (int)rows[base + min(lane, cnt - 1)];
        int j = 0;
        for (; j + 4 <= cnt; j += 4) {
            int r0 = __shfl(rl, j + es, 64);
            int r1 = __shfl(rl, j + 2 + es, 64);
            float2 h0 = A2[(size_t)r0 * 32 + ch2];
            float2 h1 = A2[(size_t)r1 * 32 + ch2];
            unsigned int e0 = EA[(size_t)(base + j + es) * 32 + ch2];
            unsigned int e1 = EA[(size_t)(base + j + 2 + es) * 32 + ch2];
            ax0 += fmaxf(h0.x + __uint_as_float(e0 << 16), 0.f);
            ay0 += fmaxf(h0.y + __uint_as_float(e0 & 0xffff0000u), 0.f);
            ax1 += fmaxf(h1.x + __uint_as_float(e1 << 16), 0.f);
            ay1 += fmaxf(h1.y + __uint_as_float(e1 & 0xffff0000u), 0.f);
        }
        for (; j < cnt; j += 2) {
            int idx = j + es;
            bool valid = idx < cnt;
            int ic = valid ? idx : (cnt - 1);
            int r0 = __shfl(rl, ic, 64);
            float2 h0 = A2[(size_t)r0 * 32 + ch2];
            unsigned int e0 = EA[(size_t)(base + ic) * 32 + ch2];
            if (valid) {
                ax0 += fmaxf(h0.x + __uint_as_float(e0 << 16), 0.f);
                ay0 += fmaxf(h0.y + __uint_as_float(e0 & 0xffff0000u), 0.f);
            }
        }
    }
    float sx = ax0 + ax1, sy = ay0 + ay1;
    sx += __shfl_xor(sx, 32, 64);
    sy += __shfl_xor(sy, 32, 64);
    if (es == 0) {
        float2 self = A2[(size_t)n * 32 + ch2];
        st2(&M[(size_t)n * 64 + ch2 * 2], self.x + sx, self.y + sy);
    }
}

// ---------- per-layer: node MLP + LN + gelu + residual ----------
// rank-1 register-tiled: 64 nodes/block, conflict-free LDS.
template <typename MT>
__global__ __launch_bounds__(256) void k_node(float* __restrict__ A, const MT* __restrict__ M,
        const float* __restrict__ cw1, const float* __restrict__ cb1,
        const float* __restrict__ cw2, const float* __restrict__ cb2,
        const float* __restrict__ lnw, const float* __restrict__ lnb) {
    __shared__ float s_W1[64 * 64];     // [k][c] row-major
    __shared__ float s_W2[64 * 64];
    __shared__ float s_m[64 * 68];      // [node][k], stride 68
    __shared__ float s_b1[64], s_b2[64], s_g[64], s_bt[64];
    int tid = threadIdx.x;
    for (int i = tid; i < 4096; i += 256) { s_W1[i] = cw1[i]; s_W2[i] = cw2[i]; }
    if (tid < 64) { s_b1[tid] = cb1[tid]; s_g[tid] = lnw[tid]; }
    else if (tid < 128) { s_b2[tid - 64] = cb2[tid - 64]; s_bt[tid - 64] = lnb[tid - 64]; }
    int nb = blockIdx.x * 64;
    for (int i = tid; i < 4096; i += 256) {
        int nl = i >> 6, k = i & 63;
        int n = nb + nl;
        s_m[nl * 68 + k] = (n < NN) ? toF(M[(size_t)n * 64 + k]) : 0.f;
    }
    __syncthreads();

    int lane = tid & 63, w = tid >> 6;
    int cq = lane & 15, ng = lane >> 4;
    int rbase = w * 16 + ng * 4;
    int c0 = cq * 4;

    float4 acc[4];
    {
        float4 b1q = *(const float4*)&s_b1[c0];
        acc[0] = b1q; acc[1] = b1q; acc[2] = b1q; acc[3] = b1q;
    }
    #pragma unroll 8
    for (int k = 0; k < 64; ++k) {
        float4 w4 = *(const float4*)&s_W1[k * 64 + c0];
        float m0 = s_m[(rbase + 0) * 68 + k];
        float m1 = s_m[(rbase + 1) * 68 + k];
        float m2 = s_m[(rbase + 2) * 68 + k];
        float m3 = s_m[(rbase + 3) * 68 + k];
        acc[0] = fma4(acc[0], m0, w4);
        acc[1] = fma4(acc[1], m1, w4);
        acc[2] = fma4(acc[2], m2, w4);
        acc[3] = fma4(acc[3], m3, w4);
    }
    __builtin_amdgcn_wave_barrier();
    #pragma unroll
    for (int j = 0; j < 4; ++j) {
        float4 u;
        u.x = fmaxf(acc[j].x, 0.f); u.y = fmaxf(acc[j].y, 0.f);
        u.z = fmaxf(acc[j].z, 0.f); u.w = fmaxf(acc[j].w, 0.f);
        *(float4*)&s_m[(rbase + j) * 68 + c0] = u;
    }
    __builtin_amdgcn_wave_barrier();

    {
        float4 b2q = *(const float4*)&s_b2[c0];
        acc[0] = b2q; acc[1] = b2q; acc[2] = b2q; acc[3] = b2q;
    }
    #pragma unroll 8
    for (int k = 0; k < 64; ++k) {
        float4 w4 = *(const float4*)&s_W2[k * 64 + c0];
        float m0 = s_m[(rbase + 0) * 68 + k];
        float m1 = s_m[(rbase + 1) * 68 + k];
        float m2 = s_m[(rbase + 2) * 68 + k];
        float m3 = s_m[(rbase + 3) * 68 + k];
        acc[0] = fma4(acc[0], m0, w4);
        acc[1] = fma4(acc[1], m1, w4);
        acc[2] = fma4(acc[2], m2, w4);
        acc[3] = fma4(acc[3], m3, w4);
    }

    float4 gq  = *(const float4*)&s_g[c0];
    float4 btq = *(const float4*)&s_bt[c0];
    #pragma unroll
    for (int j = 0; j < 4; ++j) {
        float4 v = acc[j];
        float sum = v.x + v.y + v.z + v.w;
        float sq  = v.x * v.x + v.y * v.y + v.z * v.z + v.w * v.w;
        #pragma unroll
        for (int m = 1; m < 16; m <<= 1) {
            sum += __shfl_xor(sum, m, 64);
            sq  += __shfl_xor(sq, m, 64);
        }
        float mu  = sum * (1.f / 64.f);
        float var = sq * (1.f / 64.f) - mu * mu;
        float rs  = rsqrtf(var + 1e-5f);
        int n = nb + rbase + j;
        if (n < NN) {
            float4 id = *(const float4*)&A[(size_t)n * 64 + c0];
            float4 o;
            float y;
            y = (v.x - mu) * rs * gq.x + btq.x; o.x = 0.5f * y * (1.f + erff(y * 0.70710678118654752f)) + id.x;
            y = (v.y - mu) * rs * gq.y + btq.y; o.y = 0.5f * y * (1.f + erff(y * 0.70710678118654752f)) + id.y;
            y = (v.z - mu) * rs * gq.z + btq.z; o.z = 0.5f * y * (1.f + erff(y * 0.70710678118654752f)) + id.z;
            y = (v.w - mu) * rs * gq.w + btq.w; o.w = 0.5f * y * (1.f + erff(y * 0.70710678118654752f)) + id.w;
            *(float4*)&A[(size_t)n * 64 + c0] = o;
        }
    }
}

// ---------- final: out = LN(h@(fw+rw) + (fb+rb); ow, ob) ----------
__global__ __launch_bounds__(256) void k_final(const float* __restrict__ h,
        const float* __restrict__ fw, const float* __restrict__ fb,
        const float* __restrict__ rw, const float* __restrict__ rb,
        const float* __restrict__ ow, const float* __restrict__ ob,
        float* __restrict__ out) {
    __shared__ float s_W[64 * 128];     // [k][c] row-major, combined fw+rw
    __shared__ float s_h[32 * 68];
    __shared__ float s_b[128];
    __shared__ float s_red[32][4];
    int tid = threadIdx.x;
    for (int i = tid; i < 8192; i += 256) s_W[i] = fw[i] + rw[i];
    if (tid < 128) s_b[tid] = fb[tid] + rb[tid];
    int nb = blockIdx.x * 32;
    for (int i = tid; i < 2048; i += 256) {
        int nl = i >> 6, k = i & 63;
        int n = nb + nl;
        s_h[nl * 68 + k] = (n < NN) ? h[(size_t)n * 64 + k] : 0.f;
    }
    __syncthreads();

    int lane = tid & 63, w = tid >> 6;
    int chh = w & 1, nh = w >> 1;
    int cq = lane & 15, ng = lane >> 4;
    int c0 = chh * 64 + cq * 4;
    int rbase = nh * 16 + ng * 4;

    float4 acc[4];
    {
        float4 bq = *(const float4*)&s_b[c0];
        acc[0] = bq; acc[1] = bq; acc[2] = bq; acc[3] = bq;
    }
    #pragma unroll 8
    for (int k = 0; k < 64; ++k) {
        float4 w4 = *(const float4*)&s_W[k * 128 + c0];
        float m0 = s_h[(rbase + 0) * 68 + k];
        float m1 = s_h[(rbase + 1) * 68 + k];
        float m2 = s_h[(rbase + 2) * 68 + k];
        float m3 = s_h[(rbase + 3) * 68 + k];
        acc[0] = fma4(acc[0], m0, w4);
        acc[1] = fma4(acc[1], m1, w4);
        acc[2] = fma4(acc[2], m2, w4);
        acc[3] = fma4(acc[3], m3, w4);
    }
    #pragma unroll
    for (int j = 0; j < 4; ++j) {
        float4 v = acc[j];
        float sum = v.x + v.y + v.z + v.w;
        float sq  = v.x * v.x + v.y * v.y + v.z * v.z + v.w * v.w;
        #pragma unroll
        for (int m = 1; m < 16; m <<= 1) {
            sum += __shfl_xor(sum, m, 64);
            sq  += __shfl_xor(sq, m, 64);
        }
        if (cq == 0) {
            s_red[rbase + j][chh * 2]     = sum;
            s_red[rbase + j][chh * 2 + 1] = sq;
        }
    }
    __syncthreads();
    float4 gq = *(const float4*)&ow[c0];
    float4 bq = *(const float4*)&ob[c0];
    #pragma unroll
    for (int j = 0; j < 4; ++j) {
        int nl = rbase + j;
        int n = nb + nl;
        float tsum = s_red[nl][0] + s_red[nl][2];
        float tsq  = s_red[nl][1] + s_red[nl][3];
        float mu  = tsum * (1.f / 128.f);
        float var = tsq * (1.f / 128.f) - mu * mu;
        float rs  = rsqrtf(var + 1e-5f);
        if (n < NN) {
            float4 v = acc[j];
            float4 o;
            o.x = (v.x - mu) * rs * gq.x + bq.x;
            o.y = (v.y - mu) * rs * gq.y + bq.y;
            o.z = (v.z - mu) * rs * gq.z + bq.z;
            o.w = (v.w - mu) * rs * gq.w + bq.w;
            *(float4*)&out[(size_t)n * 128 + c0] = o;
        }
    }
}

extern "C" void kernel_launch(void* const* d_in, const int* in_sizes, int n_in,
                              void* d_out, int out_size, void* d_ws, size_t ws_size,
                              hipStream_t stream) {
    const float* x    = (const float*)d_in[0];
    const int*   ei   = (const int*)d_in[1];
    const float* in_w = (const float*)d_in[2];
    const float* in_b = (const float*)d_in[3];
    const float* ew1  = (const float*)d_in[4];
    const float* eb1  = (const float*)d_in[5];
    const float* ew2  = (const float*)d_in[6];
    const float* eb2  = (const float*)d_in[7];
    const float* cw1  = (const float*)d_in[8];
    const float* cb1  = (const float*)d_in[9];
    const float* cw2  = (const float*)d_in[10];
    const float* cb2  = (const float*)d_in[11];
    const float* lnw  = (const float*)d_in[12];
    const float* lnb  = (const float*)d_in[13];
    const float* fw   = (const float*)d_in[14];
    const float* fb   = (const float*)d_in[15];
    const float* rw   = (const float*)d_in[16];
    const float* rb   = (const float*)d_in[17];
    const float* ow   = (const float*)d_in[18];
    const float* ob   = (const float*)d_in[19];
    float* out = (float*)d_out;

    // workspace layout (bytes):
    //   ea     : NE*64*2            = 102,400,000     @ 0
    //   A (h)  : NN*64*4            =  12,800,000     @ 102,400,000
    //   rows   : NE*2 (u16)         =   1,600,000     @ 115,200,000
    //   offcur : (NN+1)*4 (+pad)    =     200,016     @ 116,800,000
    //   M      : NN*64*{4|2}        =  12.8M | 6.4M   @ 117,000,016
    //   dpos   : NE*4 = 3.2M  (aliases M region; dead before layer 0)
    char* ws = (char*)d_ws;
    unsigned short* ea   = (unsigned short*)ws;
    float*          A    = (float*)(ws + 102400000);
    unsigned short* rows = (unsigned short*)(ws + 115200000);
    int*            off  = (int*)(ws + 116800000);
    char*           Mp   = ws + 117000016;
    int*            dpos = (int*)Mp;

    const bool m32 = (ws_size >= 129800016ull);

    hipMemsetAsync(off, 0, (NN + 1) * sizeof(int), stream);
    k_deg<<<NE / 256, 256, 0, stream>>>(ei, off);
    k_scan<<<1, 1024, 0, stream>>>(off);
    k_scatter<<<NE / 256, 256, 0, stream>>>(ei, off, rows, dpos);
    k_input<<<NN / 4, 256, 0, stream>>>(x, in_w, in_b, A);
    k_edge<<<NE / 64, 256, 0, stream>>>(x, ei, ew1, eb1, ew2, eb2, dpos, ea);

    const int nodeBlocks = (NN + 63) / 64;     // 782
    for (int l = 0; l < 4; ++l) {
        const float* w1 = cw1 + (size_t)l * 4096;
        const float* b1 = cb1 + (size_t)l * 64;
        const float* w2 = cw2 + (size_t)l * 4096;
        const float* b2 = cb2 + (size_t)l * 64;
        const float* g  = lnw + (size_t)l * 64;
        const float* bt = lnb + (size_t)l * 64;
        if (m32) {
            k_agg<float><<<NN / 4, 256, 0, stream>>>(A, ea, rows, off, (float*)Mp);
            k_node<float><<<nodeBlocks, 256, 0, stream>>>(A, (const float*)Mp, w1, b1, w2, b2, g, bt);
        } else {
            k_agg<__half><<<NN / 4, 256, 0, stream>>>(A, ea, rows, off, (__half*)Mp);
            k_node<__half><<<nodeBlocks, 256, 0, stream>>>(A, (const __half*)Mp, w1, b1, w2, b2, g, bt);
        }
    }
    k_final<<<(NN + 31) / 32, 256, 0, stream>>>(A, fw, fb, rw, rb, ow, ob, out);
}

// Round 5
// 568.392 us; speedup vs baseline: 5.8210x; 1.1533x over previous
//
#include <hip/hip_runtime.h>
#include <hip/hip_fp16.h>
#include <stdint.h>

#define NN 50000
#define NE 800000
#define SCAN_BLOCKS 196   // 196*256 = 50176 >= NN

typedef short short8 __attribute__((ext_vector_type(8)));
typedef float f32x4 __attribute__((ext_vector_type(4)));

static __device__ __forceinline__ unsigned short f2bf(float f) {
    unsigned int u = __float_as_uint(f);
    u += 0x7fffu + ((u >> 16) & 1u);   // round-to-nearest-even
    return (unsigned short)(u >> 16);
}
static __device__ __forceinline__ float toF(float v) { return v; }
static __device__ __forceinline__ float toF(__half v) { return __half2float(v); }

static __device__ __forceinline__ void st4(float* p, float4 v) {
    *(float4*)p = v;
}
static __device__ __forceinline__ void st4(__half* p, float4 v) {
    ushort4 o;
    o.x = __half_as_ushort(__float2half(v.x));
    o.y = __half_as_ushort(__float2half(v.y));
    o.z = __half_as_ushort(__float2half(v.z));
    o.w = __half_as_ushort(__float2half(v.w));
    *(ushort4*)p = o;
}

static __device__ __forceinline__ float4 fma4(float4 a, float s, float4 w) {
    a.x = fmaf(s, w.x, a.x); a.y = fmaf(s, w.y, a.y);
    a.z = fmaf(s, w.z, a.z); a.w = fmaf(s, w.w, a.w);
    return a;
}
static __device__ __forceinline__ void accbf(float4& acc, float4 h, uint2 e) {
    acc.x += fmaxf(h.x + __uint_as_float(e.x << 16), 0.f);
    acc.y += fmaxf(h.y + __uint_as_float(e.x & 0xffff0000u), 0.f);
    acc.z += fmaxf(h.z + __uint_as_float(e.y << 16), 0.f);
    acc.w += fmaxf(h.w + __uint_as_float(e.y & 0xffff0000u), 0.f);
}

// ---------- CSR build ----------
__global__ __launch_bounds__(256) void k_deg(const int* __restrict__ ei, int* __restrict__ offcur) {
    int e = blockIdx.x * 256 + threadIdx.x;
    atomicAdd(&offcur[ei[NE + e]], 1);
}

// hierarchical scan: A) per-block sums
__global__ __launch_bounds__(256) void k_scanA(const int* __restrict__ off, int* __restrict__ part) {
    __shared__ int s[256];
    int t = threadIdx.x;
    int idx = blockIdx.x * 256 + t;
    int d = (idx < NN) ? off[idx] : 0;
    s[t] = d; __syncthreads();
    for (int o = 128; o > 0; o >>= 1) {
        if (t < o) s[t] += s[t + o];
        __syncthreads();
    }
    if (t == 0) part[blockIdx.x] = s[0];
}

// B) exclusive scan of the block sums (single small block)
__global__ __launch_bounds__(256) void k_scanB(int* __restrict__ part) {
    __shared__ int s[256];
    int t = threadIdx.x;
    int d = (t < SCAN_BLOCKS) ? part[t] : 0;
    s[t] = d; __syncthreads();
    #pragma unroll
    for (int o = 1; o < 256; o <<= 1) {
        int v = (t >= o) ? s[t - o] : 0;
        __syncthreads();
        s[t] += v;
        __syncthreads();
    }
    if (t < SCAN_BLOCKS) part[t] = s[t] - d;   // exclusive
}

// C) per-block exclusive scan + base
__global__ __launch_bounds__(256) void k_scanC(int* __restrict__ off, const int* __restrict__ part) {
    __shared__ int s[256];
    int t = threadIdx.x;
    int idx = blockIdx.x * 256 + t;
    int d = (idx < NN) ? off[idx] : 0;
    s[t] = d; __syncthreads();
    #pragma unroll
    for (int o = 1; o < 256; o <<= 1) {
        int v = (t >= o) ? s[t - o] : 0;
        __syncthreads();
        s[t] += v;
        __syncthreads();
    }
    if (idx < NN) off[idx] = s[t] - d + part[blockIdx.x];
}

__global__ __launch_bounds__(256) void k_scatter(const int* __restrict__ ei,
        int* __restrict__ offcur, unsigned short* __restrict__ rows, int* __restrict__ dpos) {
    int e = blockIdx.x * 256 + threadIdx.x;
    int col = ei[NE + e];
    int pos = atomicAdd(&offcur[col], 1);
    rows[pos] = (unsigned short)ei[e];
    dpos[e] = pos;
}

// ---------- h init ----------
__global__ __launch_bounds__(256) void k_input(const float* __restrict__ x,
        const float* __restrict__ in_w, const float* __restrict__ in_b,
        float* __restrict__ h) {
    int n = blockIdx.x * 4 + (threadIdx.x >> 6);
    int k = threadIdx.x & 63;
    const float* xr = x + (size_t)n * 3;
    h[(size_t)n * 64 + k] = in_b[k] + xr[0] * in_w[k] + xr[1] * in_w[64 + k] + xr[2] * in_w[128 + k];
}

// ---------- edge MLP -> ea (bf16) via MFMA, written in dest-sorted order ----------
__global__ __launch_bounds__(256) void k_edge(const float* __restrict__ x,
        const int* __restrict__ ei,
        const float* __restrict__ ew1, const float* __restrict__ eb1,
        const float* __restrict__ ew2, const float* __restrict__ eb2,
        const int* __restrict__ dpos, unsigned short* __restrict__ ea) {
    __shared__ unsigned short s_w2f[8][64][8];   // [kt*4+nt][lane][j]  (B-frags)
    __shared__ unsigned short s_t[64][72];       // t, [edge][k] padded
    __shared__ unsigned short s_d[64][72];       // D staging, [edge][c] padded
    __shared__ float s_w1[128], s_b1[64], s_b2[64];
    int tid = threadIdx.x;

    for (int i = tid; i < 4096; i += 256) {
        int k = i >> 6, n = i & 63;
        int kt = k >> 5, kin = k & 31;
        int quad = kin >> 3, j = kin & 7;
        int nt = n >> 4, nin = n & 15;
        s_w2f[kt * 4 + nt][quad * 16 + nin][j] = f2bf(ew2[i]);
    }
    if (tid < 128) s_w1[tid] = ew1[tid];
    if (tid < 64) s_b1[tid] = eb1[tid];
    else if (tid < 128) s_b2[tid - 64] = eb2[tid - 64];

    int eb = blockIdx.x * 64;
    int et = tid & 63;
    int jb = tid >> 6;
    {
        int e = eb + et;
        int r = ei[e], c = ei[NE + e];
        float rx = x[(size_t)c * 3]     - x[(size_t)r * 3];
        float ry = x[(size_t)c * 3 + 1] - x[(size_t)r * 3 + 1];
        __syncthreads();
        #pragma unroll
        for (int jj = 0; jj < 16; ++jj) {
            int j = jb * 16 + jj;
            float t = fmaxf(rx * s_w1[j] + ry * s_w1[64 + j] + s_b1[j], 0.f);
            s_t[et][j] = f2bf(t);
        }
    }
    __syncthreads();

    int w = tid >> 6, lane = tid & 63;
    int lm = lane & 15, lq = lane >> 4;
    f32x4 acc[4];
    #pragma unroll
    for (int nt = 0; nt < 4; ++nt) {
        float b = s_b2[nt * 16 + lm];
        acc[nt][0] = b; acc[nt][1] = b; acc[nt][2] = b; acc[nt][3] = b;
    }
    #pragma unroll
    for (int kt = 0; kt < 2; ++kt) {
        short8 a = *(const short8*)&s_t[w * 16 + lm][kt * 32 + lq * 8];
        #pragma unroll
        for (int nt = 0; nt < 4; ++nt) {
            short8 b = *(const short8*)&s_w2f[kt * 4 + nt][lane][0];
            acc[nt] = __builtin_amdgcn_mfma_f32_16x16x32_bf16(a, b, acc[nt], 0, 0, 0);
        }
    }

    #pragma unroll
    for (int nt = 0; nt < 4; ++nt) {
        #pragma unroll
        for (int r = 0; r < 4; ++r) {
            int row = w * 16 + lq * 4 + r;
            s_d[row][nt * 16 + lm] = f2bf(acc[nt][r]);
        }
    }
    __syncthreads();

    int row = tid >> 2, seg = tid & 3;
    int pos = dpos[eb + row];
    uint4 v0 = *(const uint4*)&s_d[row][seg * 16];
    uint4 v1 = *(const uint4*)&s_d[row][seg * 16 + 8];
    uint4* dst = (uint4*)&ea[(size_t)pos * 64 + seg * 16];
    dst[0] = v0;
    dst[1] = v1;
}

// ---------- per-layer: gather aggregate (atomic-free) ----------
// wave per node; lane = es (4 edge sublanes) x ch (16 channel quads).
// per 4 edges: one float4 h-load + one uint2 ea-load per lane.
template <typename MT>
__global__ __launch_bounds__(256) void k_agg(const float* __restrict__ A,
        const unsigned short* __restrict__ ea, const unsigned short* __restrict__ rows,
        const int* __restrict__ offcur, MT* __restrict__ M) {
    const float4* A4 = (const float4*)A;
    const uint2* EA2 = (const uint2*)ea;
    int w = threadIdx.x >> 6, lane = threadIdx.x & 63;
    int es = lane >> 4, ch = lane & 15;
    int n = blockIdx.x * 4 + w;
    int p0 = (n == 0) ? 0 : offcur[n - 1];
    int p1 = offcur[n];
    float4 acc = {0,0,0,0}, accB = {0,0,0,0};
    for (int base = p0; base < p1; base += 64) {
        int cnt = min(64, p1 - base);
        int rl = (int)rows[base + min(lane, cnt - 1)];
        int j = 0;
        for (; j + 8 <= cnt; j += 8) {
            int i0 = j + es, i1 = j + 4 + es;
            int r0 = __shfl(rl, i0, 64);
            int r1 = __shfl(rl, i1, 64);
            float4 h0 = A4[(size_t)r0 * 16 + ch];
            float4 h1 = A4[(size_t)r1 * 16 + ch];
            uint2 e0 = EA2[(size_t)(base + i0) * 16 + ch];
            uint2 e1 = EA2[(size_t)(base + i1) * 16 + ch];
            accbf(acc, h0, e0);
            accbf(accB, h1, e1);
        }
        for (; j < cnt; j += 4) {
            int i0 = j + es;
            bool valid = i0 < cnt;
            int ic = valid ? i0 : (cnt - 1);
            int r0 = __shfl(rl, ic, 64);
            float4 h0 = A4[(size_t)r0 * 16 + ch];
            uint2 e0 = EA2[(size_t)(base + ic) * 16 + ch];
            if (valid) accbf(acc, h0, e0);
        }
    }
    acc.x += accB.x; acc.y += accB.y; acc.z += accB.z; acc.w += accB.w;
    #pragma unroll
    for (int m = 16; m < 64; m <<= 1) {
        acc.x += __shfl_xor(acc.x, m, 64);
        acc.y += __shfl_xor(acc.y, m, 64);
        acc.z += __shfl_xor(acc.z, m, 64);
        acc.w += __shfl_xor(acc.w, m, 64);
    }
    if (es == 0) {
        float4 self = A4[(size_t)n * 16 + ch];
        float4 o;
        o.x = self.x + acc.x; o.y = self.y + acc.y;
        o.z = self.z + acc.z; o.w = self.w + acc.w;
        st4(&M[(size_t)n * 64 + ch * 4], o);
    }
}

// ---------- per-layer: node MLP + LN + gelu + residual ----------
template <typename MT>
__global__ __launch_bounds__(256) void k_node(float* __restrict__ A, const MT* __restrict__ M,
        const float* __restrict__ cw1, const float* __restrict__ cb1,
        const float* __restrict__ cw2, const float* __restrict__ cb2,
        const float* __restrict__ lnw, const float* __restrict__ lnb) {
    __shared__ float s_W1[64 * 64];     // [k][c] row-major
    __shared__ float s_W2[64 * 64];
    __shared__ float s_m[64 * 68];      // [node][k], stride 68
    __shared__ float s_b1[64], s_b2[64], s_g[64], s_bt[64];
    int tid = threadIdx.x;
    for (int i = tid; i < 4096; i += 256) { s_W1[i] = cw1[i]; s_W2[i] = cw2[i]; }
    if (tid < 64) { s_b1[tid] = cb1[tid]; s_g[tid] = lnw[tid]; }
    else if (tid < 128) { s_b2[tid - 64] = cb2[tid - 64]; s_bt[tid - 64] = lnb[tid - 64]; }
    int nb = blockIdx.x * 64;
    for (int i = tid; i < 4096; i += 256) {
        int nl = i >> 6, k = i & 63;
        int n = nb + nl;
        s_m[nl * 68 + k] = (n < NN) ? toF(M[(size_t)n * 64 + k]) : 0.f;
    }
    __syncthreads();

    int lane = tid & 63, w = tid >> 6;
    int cq = lane & 15, ng = lane >> 4;
    int rbase = w * 16 + ng * 4;
    int c0 = cq * 4;

    float4 acc[4];
    {
        float4 b1q = *(const float4*)&s_b1[c0];
        acc[0] = b1q; acc[1] = b1q; acc[2] = b1q; acc[3] = b1q;
    }
    #pragma unroll 8
    for (int k = 0; k < 64; ++k) {
        float4 w4 = *(const float4*)&s_W1[k * 64 + c0];
        float m0 = s_m[(rbase + 0) * 68 + k];
        float m1 = s_m[(rbase + 1) * 68 + k];
        float m2 = s_m[(rbase + 2) * 68 + k];
        float m3 = s_m[(rbase + 3) * 68 + k];
        acc[0] = fma4(acc[0], m0, w4);
        acc[1] = fma4(acc[1], m1, w4);
        acc[2] = fma4(acc[2], m2, w4);
        acc[3] = fma4(acc[3], m3, w4);
    }
    __builtin_amdgcn_wave_barrier();
    #pragma unroll
    for (int j = 0; j < 4; ++j) {
        float4 u;
        u.x = fmaxf(acc[j].x, 0.f); u.y = fmaxf(acc[j].y, 0.f);
        u.z = fmaxf(acc[j].z, 0.f); u.w = fmaxf(acc[j].w, 0.f);
        *(float4*)&s_m[(rbase + j) * 68 + c0] = u;
    }
    __builtin_amdgcn_wave_barrier();

    {
        float4 b2q = *(const float4*)&s_b2[c0];
        acc[0] = b2q; acc[1] = b2q; acc[2] = b2q; acc[3] = b2q;
    }
    #pragma unroll 8
    for (int k = 0; k < 64; ++k) {
        float4 w4 = *(const float4*)&s_W2[k * 64 + c0];
        float m0 = s_m[(rbase + 0) * 68 + k];
        float m1 = s_m[(rbase + 1) * 68 + k];
        float m2 = s_m[(rbase + 2) * 68 + k];
        float m3 = s_m[(rbase + 3) * 68 + k];
        acc[0] = fma4(acc[0], m0, w4);
        acc[1] = fma4(acc[1], m1, w4);
        acc[2] = fma4(acc[2], m2, w4);
        acc[3] = fma4(acc[3], m3, w4);
    }

    float4 gq  = *(const float4*)&s_g[c0];
    float4 btq = *(const float4*)&s_bt[c0];
    #pragma unroll
    for (int j = 0; j < 4; ++j) {
        float4 v = acc[j];
        float sum = v.x + v.y + v.z + v.w;
        float sq  = v.x * v.x + v.y * v.y + v.z * v.z + v.w * v.w;
        #pragma unroll
        for (int m = 1; m < 16; m <<= 1) {
            sum += __shfl_xor(sum, m, 64);
            sq  += __shfl_xor(sq, m, 64);
        }
        float mu  = sum * (1.f / 64.f);
        float var = sq * (1.f / 64.f) - mu * mu;
        float rs  = rsqrtf(var + 1e-5f);
        int n = nb + rbase + j;
        if (n < NN) {
            float4 id = *(const float4*)&A[(size_t)n * 64 + c0];
            float4 o;
            float y;
            y = (v.x - mu) * rs * gq.x + btq.x; o.x = 0.5f * y * (1.f + erff(y * 0.70710678118654752f)) + id.x;
            y = (v.y - mu) * rs * gq.y + btq.y; o.y = 0.5f * y * (1.f + erff(y * 0.70710678118654752f)) + id.y;
            y = (v.z - mu) * rs * gq.z + btq.z; o.z = 0.5f * y * (1.f + erff(y * 0.70710678118654752f)) + id.z;
            y = (v.w - mu) * rs * gq.w + btq.w; o.w = 0.5f * y * (1.f + erff(y * 0.70710678118654752f)) + id.w;
            *(float4*)&A[(size_t)n * 64 + c0] = o;
        }
    }
}

// ---------- final: out = LN(h@(fw+rw) + (fb+rb); ow, ob) ----------
__global__ __launch_bounds__(256) void k_final(const float* __restrict__ h,
        const float* __restrict__ fw, const float* __restrict__ fb,
        const float* __restrict__ rw, const float* __restrict__ rb,
        const float* __restrict__ ow, const float* __restrict__ ob,
        float* __restrict__ out) {
    __shared__ float s_W[64 * 128];     // [k][c] row-major, combined fw+rw
    __shared__ float s_h[32 * 68];
    __shared__ float s_b[128];
    __shared__ float s_red[32][4];
    int tid = threadIdx.x;
    for (int i = tid; i < 8192; i += 256) s_W[i] = fw[i] + rw[i];
    if (tid < 128) s_b[tid] = fb[tid] + rb[tid];
    int nb = blockIdx.x * 32;
    for (int i = tid; i < 2048; i += 256) {
        int nl = i >> 6, k = i & 63;
        int n = nb + nl;
        s_h[nl * 68 + k] = (n < NN) ? h[(size_t)n * 64 + k] : 0.f;
    }
    __syncthreads();

    int lane = tid & 63, w = tid >> 6;
    int chh = w & 1, nh = w >> 1;
    int cq = lane & 15, ng = lane >> 4;
    int c0 = chh * 64 + cq * 4;
    int rbase = nh * 16 + ng * 4;

    float4 acc[4];
    {
        float4 bq = *(const float4*)&s_b[c0];
        acc[0] = bq; acc[1] = bq; acc[2] = bq; acc[3] = bq;
    }
    #pragma unroll 8
    for (int k = 0; k < 64; ++k) {
        float4 w4 = *(const float4*)&s_W[k * 128 + c0];
        float m0 = s_h[(rbase + 0) * 68 + k];
        float m1 = s_h[(rbase + 1) * 68 + k];
        float m2 = s_h[(rbase + 2) * 68 + k];
        float m3 = s_h[(rbase + 3) * 68 + k];
        acc[0] = fma4(acc[0], m0, w4);
        acc[1] = fma4(acc[1], m1, w4);
        acc[2] = fma4(acc[2], m2, w4);
        acc[3] = fma4(acc[3], m3, w4);
    }
    #pragma unroll
    for (int j = 0; j < 4; ++j) {
        float4 v = acc[j];
        float sum = v.x + v.y + v.z + v.w;
        float sq  = v.x * v.x + v.y * v.y + v.z * v.z + v.w * v.w;
        #pragma unroll
        for (int m = 1; m < 16; m <<= 1) {
            sum += __shfl_xor(sum, m, 64);
            sq  += __shfl_xor(sq, m, 64);
        }
        if (cq == 0) {
            s_red[rbase + j][chh * 2]     = sum;
            s_red[rbase + j][chh * 2 + 1] = sq;
        }
    }
    __syncthreads();
    float4 gq = *(const float4*)&ow[c0];
    float4 bq = *(const float4*)&ob[c0];
    #pragma unroll
    for (int j = 0; j < 4; ++j) {
        int nl = rbase + j;
        int n = nb + nl;
        float tsum = s_red[nl][0] + s_red[nl][2];
        float tsq  = s_red[nl][1] + s_red[nl][3];
        float mu  = tsum * (1.f / 128.f);
        float var = tsq * (1.f / 128.f) - mu * mu;
        float rs  = rsqrtf(var + 1e-5f);
        if (n < NN) {
            float4 v = acc[j];
            float4 o;
            o.x = (v.x - mu) * rs * gq.x + bq.x;
            o.y = (v.y - mu) * rs * gq.y + bq.y;
            o.z = (v.z - mu) * rs * gq.z + bq.z;
            o.w = (v.w - mu) * rs * gq.w + bq.w;
            *(float4*)&out[(size_t)n * 128 + c0] = o;
        }
    }
}

extern "C" void kernel_launch(void* const* d_in, const int* in_sizes, int n_in,
                              void* d_out, int out_size, void* d_ws, size_t ws_size,
                              hipStream_t stream) {
    const float* x    = (const float*)d_in[0];
    const int*   ei   = (const int*)d_in[1];
    const float* in_w = (const float*)d_in[2];
    const float* in_b = (const float*)d_in[3];
    const float* ew1  = (const float*)d_in[4];
    const float* eb1  = (const float*)d_in[5];
    const float* ew2  = (const float*)d_in[6];
    const float* eb2  = (const float*)d_in[7];
    const float* cw1  = (const float*)d_in[8];
    const float* cb1  = (const float*)d_in[9];
    const float* cw2  = (const float*)d_in[10];
    const float* cb2  = (const float*)d_in[11];
    const float* lnw  = (const float*)d_in[12];
    const float* lnb  = (const float*)d_in[13];
    const float* fw   = (const float*)d_in[14];
    const float* fb   = (const float*)d_in[15];
    const float* rw   = (const float*)d_in[16];
    const float* rb   = (const float*)d_in[17];
    const float* ow   = (const float*)d_in[18];
    const float* ob   = (const float*)d_in[19];
    float* out = (float*)d_out;

    // workspace layout (bytes):
    //   ea     : NE*64*2            = 102,400,000     @ 0
    //   A (h)  : NN*64*4            =  12,800,000     @ 102,400,000
    //   rows   : NE*2 (u16)         =   1,600,000     @ 115,200,000
    //   offcur : (NN+1)*4 (+pad)    =     200,016     @ 116,800,000
    //   M      : NN*64*{4|2}        =  12.8M | 6.4M   @ 117,000,016
    //   dpos   : NE*4 = 3.2M  (aliases M region; dead before layer 0)
    //   part   : SCAN_BLOCKS*4      (aliases M region after dpos; dead before layer 0)
    char* ws = (char*)d_ws;
    unsigned short* ea   = (unsigned short*)ws;
    float*          A    = (float*)(ws + 102400000);
    unsigned short* rows = (unsigned short*)(ws + 115200000);
    int*            off  = (int*)(ws + 116800000);
    char*           Mp   = ws + 117000016;
    int*            dpos = (int*)Mp;
    int*            part = (int*)(Mp + 3200000);

    const bool m32 = (ws_size >= 129800016ull);

    hipMemsetAsync(off, 0, (NN + 1) * sizeof(int), stream);
    k_deg<<<NE / 256, 256, 0, stream>>>(ei, off);
    k_scanA<<<SCAN_BLOCKS, 256, 0, stream>>>(off, part);
    k_scanB<<<1, 256, 0, stream>>>(part);
    k_scanC<<<SCAN_BLOCKS, 256, 0, stream>>>(off, part);
    k_scatter<<<NE / 256, 256, 0, stream>>>(ei, off, rows, dpos);
    k_input<<<NN / 4, 256, 0, stream>>>(x, in_w, in_b, A);
    k_edge<<<NE / 64, 256, 0, stream>>>(x, ei, ew1, eb1, ew2, eb2, dpos, ea);

    const int nodeBlocks = (NN + 63) / 64;     // 782
    for (int l = 0; l < 4; ++l) {
        const float* w1 = cw1 + (size_t)l * 4096;
        const float* b1 = cb1 + (size_t)l * 64;
        const float* w2 = cw2 + (size_t)l * 4096;
        const float* b2 = cb2 + (size_t)l * 64;
        const float* g  = lnw + (size_t)l * 64;
        const float* bt = lnb + (size_t)l * 64;
        if (m32) {
            k_agg<float><<<NN / 4, 256, 0, stream>>>(A, ea, rows, off, (float*)Mp);
            k_node<float><<<nodeBlocks, 256, 0, stream>>>(A, (const float*)Mp, w1, b1, w2, b2, g, bt);
        } else {
            k_agg<__half><<<NN / 4, 256, 0, stream>>>(A, ea, rows, off, (__half*)Mp);
            k_node<__half><<<nodeBlocks, 256, 0, stream>>>(A, (const __half*)Mp, w1, b1, w2, b2, g, bt);
        }
    }
    k_final<<<(NN + 31) / 32, 256, 0, stream>>>(A, fw, fb, rw, rb, ow, ob, out);
}

// Round 7
// 507.779 us; speedup vs baseline: 6.5158x; 1.1194x over previous
//
#include <hip/hip_runtime.h>
#include <hip/hip_fp16.h>
#include <stdint.h>

#define NN 50000
#define NE 800000
#define SCAN_BLOCKS 196   // 196*256 = 50176 >= NN

typedef _Float16 half8v __attribute__((ext_vector_type(8)));
typedef float f32x4 __attribute__((ext_vector_type(4)));

static __device__ __forceinline__ __half2 u2h2(unsigned int u) {
    union { unsigned int u; __half2 h; } c; c.u = u; return c.h;
}
static __device__ __forceinline__ unsigned int h22u(__half2 h) {
    union { __half2 h; unsigned int u; } c; c.h = h; return c.u;
}

static __device__ __forceinline__ float4 fma4(float4 a, float s, float4 w) {
    a.x = fmaf(s, w.x, a.x); a.y = fmaf(s, w.y, a.y);
    a.z = fmaf(s, w.z, a.z); a.w = fmaf(s, w.w, a.w);
    return a;
}
// acc += relu(h + e); h/e packed fp16 x4, math in fp32
static __device__ __forceinline__ void acch(float4& acc, uint2 h, uint2 e) {
    float2 h0 = __half22float2(u2h2(h.x));
    float2 h1 = __half22float2(u2h2(h.y));
    float2 e0 = __half22float2(u2h2(e.x));
    float2 e1 = __half22float2(u2h2(e.y));
    acc.x += fmaxf(h0.x + e0.x, 0.f);
    acc.y += fmaxf(h0.y + e0.y, 0.f);
    acc.z += fmaxf(h1.x + e1.x, 0.f);
    acc.w += fmaxf(h1.y + e1.y, 0.f);
}

// ---------- CSR build ----------
__global__ __launch_bounds__(256) void k_deg(const int* __restrict__ ei, int* __restrict__ offcur) {
    int e = blockIdx.x * 256 + threadIdx.x;
    atomicAdd(&offcur[ei[NE + e]], 1);
}

__global__ __launch_bounds__(256) void k_scanA(const int* __restrict__ off, int* __restrict__ part) {
    __shared__ int s[256];
    int t = threadIdx.x;
    int idx = blockIdx.x * 256 + t;
    int d = (idx < NN) ? off[idx] : 0;
    s[t] = d; __syncthreads();
    for (int o = 128; o > 0; o >>= 1) {
        if (t < o) s[t] += s[t + o];
        __syncthreads();
    }
    if (t == 0) part[blockIdx.x] = s[0];
}

__global__ __launch_bounds__(256) void k_scanB(int* __restrict__ part) {
    __shared__ int s[256];
    int t = threadIdx.x;
    int d = (t < SCAN_BLOCKS) ? part[t] : 0;
    s[t] = d; __syncthreads();
    #pragma unroll
    for (int o = 1; o < 256; o <<= 1) {
        int v = (t >= o) ? s[t - o] : 0;
        __syncthreads();
        s[t] += v;
        __syncthreads();
    }
    if (t < SCAN_BLOCKS) part[t] = s[t] - d;   // exclusive
}

__global__ __launch_bounds__(256) void k_scanC(int* __restrict__ off, const int* __restrict__ part) {
    __shared__ int s[256];
    int t = threadIdx.x;
    int idx = blockIdx.x * 256 + t;
    int d = (idx < NN) ? off[idx] : 0;
    s[t] = d; __syncthreads();
    #pragma unroll
    for (int o = 1; o < 256; o <<= 1) {
        int v = (t >= o) ? s[t - o] : 0;
        __syncthreads();
        s[t] += v;
        __syncthreads();
    }
    if (idx < NN) off[idx] = s[t] - d + part[blockIdx.x];
}

__global__ __launch_bounds__(256) void k_scatter(const int* __restrict__ ei,
        int* __restrict__ offcur, unsigned short* __restrict__ rows, int* __restrict__ dpos) {
    int e = blockIdx.x * 256 + threadIdx.x;
    int col = ei[NE + e];
    int pos = atomicAdd(&offcur[col], 1);
    rows[pos] = (unsigned short)ei[e];
    dpos[e] = pos;
}

// ---------- weight prep: ew2 -> fp16 MFMA B-fragments (once) ----------
__global__ __launch_bounds__(256) void k_prep(const float* __restrict__ ew2, __half* __restrict__ w2f) {
    int tid = threadIdx.x;
    for (int i = tid; i < 4096; i += 256) {
        int k = i >> 6, n = i & 63;
        int kt = k >> 5, kin = k & 31;
        int quad = kin >> 3, j = kin & 7;
        int nt = n >> 4, nin = n & 15;
        w2f[(size_t)((kt * 4 + nt) * 64 + quad * 16 + nin) * 8 + j] = __float2half(ew2[i]);
    }
}

// ---------- h init (fp16 shadow store) ----------
__global__ __launch_bounds__(256) void k_input(const float* __restrict__ x,
        const float* __restrict__ in_w, const float* __restrict__ in_b,
        __half* __restrict__ Ah) {
    int n = blockIdx.x * 4 + (threadIdx.x >> 6);
    int k = threadIdx.x & 63;
    const float* xr = x + (size_t)n * 3;
    float v = in_b[k] + xr[0] * in_w[k] + xr[1] * in_w[64 + k] + xr[2] * in_w[128 + k];
    Ah[(size_t)n * 64 + k] = __float2half(v);
}

// ---------- edge MLP -> ea (fp16) via f16 MFMA; register A-frags, preconverted B ----------
__global__ __launch_bounds__(256) void k_edge(const float* __restrict__ x,
        const int* __restrict__ ei,
        const float* __restrict__ ew1, const float* __restrict__ eb1,
        const float* __restrict__ eb2, const __half* __restrict__ w2f,
        const int* __restrict__ dpos, __half* __restrict__ ea) {
    __shared__ float s_w1[128], s_b1[64], s_b2[64];
    __shared__ float s_rx[256], s_ry[256];
    __shared__ int s_pos[256];
    __shared__ __half s_d[4][16][80];   // per-wave staging
    int tid = threadIdx.x, lane = tid & 63, w = tid >> 6;

    half8v bf[8];
    {
        const half8v* W2F = (const half8v*)w2f;
        #pragma unroll
        for (int f = 0; f < 8; ++f) bf[f] = W2F[f * 64 + lane];
    }
    if (tid < 128) s_w1[tid] = ew1[tid];
    if (tid < 64) s_b1[tid] = eb1[tid];
    else if (tid < 128) s_b2[tid - 64] = eb2[tid - 64];
    int eb = blockIdx.x * 256;
    {
        int e = eb + tid;
        int r = ei[e], c = ei[NE + e];
        s_rx[tid] = x[(size_t)c * 3]     - x[(size_t)r * 3];
        s_ry[tid] = x[(size_t)c * 3 + 1] - x[(size_t)r * 3 + 1];
        s_pos[tid] = dpos[e];
    }
    __syncthreads();

    int lm = lane & 15, lq = lane >> 4;
    #pragma unroll
    for (int t = 0; t < 4; ++t) {
        int ebase = w * 64 + t * 16;
        float rx = s_rx[ebase + lm], ry = s_ry[ebase + lm];
        half8v a0, a1;
        #pragma unroll
        for (int j = 0; j < 8; ++j) {
            int k0 = lq * 8 + j;
            a0[j] = (_Float16)fmaxf(fmaf(rx, s_w1[k0], fmaf(ry, s_w1[64 + k0], s_b1[k0])), 0.f);
            int k1 = k0 + 32;
            a1[j] = (_Float16)fmaxf(fmaf(rx, s_w1[k1], fmaf(ry, s_w1[64 + k1], s_b1[k1])), 0.f);
        }
        f32x4 acc[4];
        #pragma unroll
        for (int nt = 0; nt < 4; ++nt) {
            float b = s_b2[nt * 16 + lm];
            acc[nt][0] = b; acc[nt][1] = b; acc[nt][2] = b; acc[nt][3] = b;
            acc[nt] = __builtin_amdgcn_mfma_f32_16x16x32_f16(a0, bf[nt],     acc[nt], 0, 0, 0);
            acc[nt] = __builtin_amdgcn_mfma_f32_16x16x32_f16(a1, bf[4 + nt], acc[nt], 0, 0, 0);
        }
        // epilogue: C/D layout col=lane&15, row=(lane>>4)*4+reg -> wave-private LDS
        __builtin_amdgcn_wave_barrier();
        #pragma unroll
        for (int nt = 0; nt < 4; ++nt)
            #pragma unroll
            for (int r = 0; r < 4; ++r)
                s_d[w][lq * 4 + r][nt * 16 + lm] = __float2half(acc[nt][r]);
        __builtin_amdgcn_wave_barrier();
        int row = lane >> 2, seg = lane & 3;
        int pos = s_pos[w * 64 + t * 16 + row];
        uint4 v0 = *(const uint4*)&s_d[w][row][seg * 16];
        uint4 v1 = *(const uint4*)&s_d[w][row][seg * 16 + 8];
        uint4* dst = (uint4*)&ea[(size_t)pos * 64 + seg * 16];
        dst[0] = v0;
        dst[1] = v1;
        __builtin_amdgcn_wave_barrier();
    }
}

// ---------- per-layer: gather aggregate (fp16 gathers, fp32 math) ----------
__global__ __launch_bounds__(256) void k_agg(const __half* __restrict__ Ah,
        const __half* __restrict__ ea, const unsigned short* __restrict__ rows,
        const int* __restrict__ offcur, float* __restrict__ M) {
    const uint2* A2 = (const uint2*)Ah;
    const uint2* E2 = (const uint2*)ea;
    int w = threadIdx.x >> 6, lane = threadIdx.x & 63;
    int es = lane >> 4, ch = lane & 15;
    int n = blockIdx.x * 4 + w;
    int p0 = (n == 0) ? 0 : offcur[n - 1];
    int p1 = offcur[n];
    float4 acc = {0,0,0,0}, accB = {0,0,0,0};
    for (int base = p0; base < p1; base += 64) {
        int cnt = min(64, p1 - base);
        int rl = (int)rows[base + min(lane, cnt - 1)];
        int j = 0;
        for (; j + 8 <= cnt; j += 8) {
            int i0 = j + es, i1 = j + 4 + es;
            int r0 = __shfl(rl, i0, 64);
            int r1 = __shfl(rl, i1, 64);
            uint2 h0 = A2[(size_t)r0 * 16 + ch];
            uint2 h1 = A2[(size_t)r1 * 16 + ch];
            uint2 e0 = E2[(size_t)(base + i0) * 16 + ch];
            uint2 e1 = E2[(size_t)(base + i1) * 16 + ch];
            acch(acc, h0, e0);
            acch(accB, h1, e1);
        }
        for (; j < cnt; j += 4) {
            int i0 = j + es;
            bool valid = i0 < cnt;
            int ic = valid ? i0 : (cnt - 1);
            int r0 = __shfl(rl, ic, 64);
            uint2 h0 = A2[(size_t)r0 * 16 + ch];
            uint2 e0 = E2[(size_t)(base + ic) * 16 + ch];
            if (valid) acch(acc, h0, e0);
        }
    }
    acc.x += accB.x; acc.y += accB.y; acc.z += accB.z; acc.w += accB.w;
    #pragma unroll
    for (int m = 16; m < 64; m <<= 1) {
        acc.x += __shfl_xor(acc.x, m, 64);
        acc.y += __shfl_xor(acc.y, m, 64);
        acc.z += __shfl_xor(acc.z, m, 64);
        acc.w += __shfl_xor(acc.w, m, 64);
    }
    if (es == 0) {
        uint2 su = A2[(size_t)n * 16 + ch];
        float2 s0 = __half22float2(u2h2(su.x));
        float2 s1 = __half22float2(u2h2(su.y));
        float4 o;
        o.x = s0.x + acc.x; o.y = s0.y + acc.y;
        o.z = s1.x + acc.z; o.w = s1.y + acc.w;
        *(float4*)&M[(size_t)n * 64 + ch * 4] = o;
    }
}

// ---------- per-layer: node MLP + LN + gelu + residual (fp16 A, f32 M) ----------
__global__ __launch_bounds__(256) void k_node(__half* __restrict__ Ah, const float* __restrict__ M,
        const float* __restrict__ cw1, const float* __restrict__ cb1,
        const float* __restrict__ cw2, const float* __restrict__ cb2,
        const float* __restrict__ lnw, const float* __restrict__ lnb) {
    __shared__ float s_W1[64 * 64];     // [k][c] row-major
    __shared__ float s_W2[64 * 64];
    __shared__ float s_m[64 * 68];      // [node][k], stride 68 (272 B = 17*16, 16B-aligned rows)
    __shared__ float s_b1[64], s_b2[64], s_g[64], s_bt[64];
    int tid = threadIdx.x;
    for (int i = tid; i < 4096; i += 256) { s_W1[i] = cw1[i]; s_W2[i] = cw2[i]; }
    if (tid < 64) { s_b1[tid] = cb1[tid]; s_g[tid] = lnw[tid]; }
    else if (tid < 128) { s_b2[tid - 64] = cb2[tid - 64]; s_bt[tid - 64] = lnb[tid - 64]; }
    int nb = blockIdx.x * 64;
    {
        const float4* M4 = (const float4*)(M + (size_t)nb * 64);
        #pragma unroll
        for (int q = 0; q < 4; ++q) {
            int i = q * 1024 + tid * 4;
            int nl = i >> 6, k = i & 63;
            float4 v = {0,0,0,0};
            if (nb + nl < NN) v = M4[i >> 2];
            *(float4*)&s_m[nl * 68 + k] = v;
        }
    }
    __syncthreads();

    int lane = tid & 63, w = tid >> 6;
    int cq = lane & 15, ng = lane >> 4;
    int rbase = w * 16 + ng * 4;
    int c0 = cq * 4;

    float4 acc[4];
    {
        float4 b1q = *(const float4*)&s_b1[c0];
        acc[0] = b1q; acc[1] = b1q; acc[2] = b1q; acc[3] = b1q;
    }
    #pragma unroll 4
    for (int k4 = 0; k4 < 16; ++k4) {
        float4 m0 = *(const float4*)&s_m[(rbase + 0) * 68 + k4 * 4];
        float4 m1 = *(const float4*)&s_m[(rbase + 1) * 68 + k4 * 4];
        float4 m2 = *(const float4*)&s_m[(rbase + 2) * 68 + k4 * 4];
        float4 m3 = *(const float4*)&s_m[(rbase + 3) * 68 + k4 * 4];
        #pragma unroll
        for (int kk = 0; kk < 4; ++kk) {
            float4 w4 = *(const float4*)&s_W1[(k4 * 4 + kk) * 64 + c0];
            acc[0] = fma4(acc[0], ((const float*)&m0)[kk], w4);
            acc[1] = fma4(acc[1], ((const float*)&m1)[kk], w4);
            acc[2] = fma4(acc[2], ((const float*)&m2)[kk], w4);
            acc[3] = fma4(acc[3], ((const float*)&m3)[kk], w4);
        }
    }
    __builtin_amdgcn_wave_barrier();
    #pragma unroll
    for (int j = 0; j < 4; ++j) {
        float4 u;
        u.x = fmaxf(acc[j].x, 0.f); u.y = fmaxf(acc[j].y, 0.f);
        u.z = fmaxf(acc[j].z, 0.f); u.w = fmaxf(acc[j].w, 0.f);
        *(float4*)&s_m[(rbase + j) * 68 + c0] = u;   // own rows only: wave-local
    }
    __builtin_amdgcn_wave_barrier();

    {
        float4 b2q = *(const float4*)&s_b2[c0];
        acc[0] = b2q; acc[1] = b2q; acc[2] = b2q; acc[3] = b2q;
    }
    #pragma unroll 4
    for (int k4 = 0; k4 < 16; ++k4) {
        float4 m0 = *(const float4*)&s_m[(rbase + 0) * 68 + k4 * 4];
        float4 m1 = *(const float4*)&s_m[(rbase + 1) * 68 + k4 * 4];
        float4 m2 = *(const float4*)&s_m[(rbase + 2) * 68 + k4 * 4];
        float4 m3 = *(const float4*)&s_m[(rbase + 3) * 68 + k4 * 4];
        #pragma unroll
        for (int kk = 0; kk < 4; ++kk) {
            float4 w4 = *(const float4*)&s_W2[(k4 * 4 + kk) * 64 + c0];
            acc[0] = fma4(acc[0], ((const float*)&m0)[kk], w4);
            acc[1] = fma4(acc[1], ((const float*)&m1)[kk], w4);
            acc[2] = fma4(acc[2], ((const float*)&m2)[kk], w4);
            acc[3] = fma4(acc[3], ((const float*)&m3)[kk], w4);
        }
    }

    float4 gq  = *(const float4*)&s_g[c0];
    float4 btq = *(const float4*)&s_bt[c0];
    #pragma unroll
    for (int j = 0; j < 4; ++j) {
        float4 v = acc[j];
        float sum = v.x + v.y + v.z + v.w;
        float sq  = v.x * v.x + v.y * v.y + v.z * v.z + v.w * v.w;
        #pragma unroll
        for (int m = 1; m < 16; m <<= 1) {
            sum += __shfl_xor(sum, m, 64);
            sq  += __shfl_xor(sq, m, 64);
        }
        float mu  = sum * (1.f / 64.f);
        float var = sq * (1.f / 64.f) - mu * mu;
        float rs  = rsqrtf(var + 1e-5f);
        int n = nb + rbase + j;
        if (n < NN) {
            uint2 iu = *(const uint2*)&Ah[(size_t)n * 64 + c0];
            float2 i0 = __half22float2(u2h2(iu.x));
            float2 i1 = __half22float2(u2h2(iu.y));
            float4 o;
            float y;
            y = (v.x - mu) * rs * gq.x + btq.x; o.x = 0.5f * y * (1.f + erff(y * 0.70710678118654752f)) + i0.x;
            y = (v.y - mu) * rs * gq.y + btq.y; o.y = 0.5f * y * (1.f + erff(y * 0.70710678118654752f)) + i0.y;
            y = (v.z - mu) * rs * gq.z + btq.z; o.z = 0.5f * y * (1.f + erff(y * 0.70710678118654752f)) + i1.x;
            y = (v.w - mu) * rs * gq.w + btq.w; o.w = 0.5f * y * (1.f + erff(y * 0.70710678118654752f)) + i1.y;
            uint2 ou;
            ou.x = h22u(__floats2half2_rn(o.x, o.y));
            ou.y = h22u(__floats2half2_rn(o.z, o.w));
            *(uint2*)&Ah[(size_t)n * 64 + c0] = ou;
        }
    }
}

// ---------- final: out = LN(h@(fw+rw) + (fb+rb); ow, ob) ----------
__global__ __launch_bounds__(256) void k_final(const __half* __restrict__ Ah,
        const float* __restrict__ fw, const float* __restrict__ fb,
        const float* __restrict__ rw, const float* __restrict__ rb,
        const float* __restrict__ ow, const float* __restrict__ ob,
        float* __restrict__ out) {
    __shared__ float s_W[64 * 128];     // [k][c] row-major, combined fw+rw
    __shared__ float s_h[32 * 68];
    __shared__ float s_b[128];
    __shared__ float s_red[32][4];
    int tid = threadIdx.x;
    for (int i = tid; i < 8192; i += 256) s_W[i] = fw[i] + rw[i];
    if (tid < 128) s_b[tid] = fb[tid] + rb[tid];
    int nb = blockIdx.x * 32;
    for (int i = tid; i < 2048; i += 256) {
        int nl = i >> 6, k = i & 63;
        int n = nb + nl;
        s_h[nl * 68 + k] = (n < NN) ? __half2float(Ah[(size_t)n * 64 + k]) : 0.f;
    }
    __syncthreads();

    int lane = tid & 63, w = tid >> 6;
    int chh = w & 1, nh = w >> 1;
    int cq = lane & 15, ng = lane >> 4;
    int c0 = chh * 64 + cq * 4;
    int rbase = nh * 16 + ng * 4;

    float4 acc[4];
    {
        float4 bq = *(const float4*)&s_b[c0];
        acc[0] = bq; acc[1] = bq; acc[2] = bq; acc[3] = bq;
    }
    #pragma unroll 4
    for (int k4 = 0; k4 < 16; ++k4) {
        float4 m0 = *(const float4*)&s_h[(rbase + 0) * 68 + k4 * 4];
        float4 m1 = *(const float4*)&s_h[(rbase + 1) * 68 + k4 * 4];
        float4 m2 = *(const float4*)&s_h[(rbase + 2) * 68 + k4 * 4];
        float4 m3 = *(const float4*)&s_h[(rbase + 3) * 68 + k4 * 4];
        #pragma unroll
        for (int kk = 0; kk < 4; ++kk) {
            float4 w4 = *(const float4*)&s_W[(k4 * 4 + kk) * 128 + c0];
            acc[0] = fma4(acc[0], ((const float*)&m0)[kk], w4);
            acc[1] = fma4(acc[1], ((const float*)&m1)[kk], w4);
            acc[2] = fma4(acc[2], ((const float*)&m2)[kk], w4);
            acc[3] = fma4(acc[3], ((const float*)&m3)[kk], w4);
        }
    }
    #pragma unroll
    for (int j = 0; j < 4; ++j) {
        float4 v = acc[j];
        float sum = v.x + v.y + v.z + v.w;
        float sq  = v.x * v.x + v.y * v.y + v.z * v.z + v.w * v.w;
        #pragma unroll
        for (int m = 1; m < 16; m <<= 1) {
            sum += __shfl_xor(sum, m, 64);
            sq  += __shfl_xor(sq, m, 64);
        }
        if (cq == 0) {
            s_red[rbase + j][chh * 2]     = sum;
            s_red[rbase + j][chh * 2 + 1] = sq;
        }
    }
    __syncthreads();
    float4 gq = *(const float4*)&ow[c0];
    float4 bq = *(const float4*)&ob[c0];
    #pragma unroll
    for (int j = 0; j < 4; ++j) {
        int nl = rbase + j;
        int n = nb + nl;
        float tsum = s_red[nl][0] + s_red[nl][2];
        float tsq  = s_red[nl][1] + s_red[nl][3];
        float mu  = tsum * (1.f / 128.f);
        float var = tsq * (1.f / 128.f) - mu * mu;
        float rs  = rsqrtf(var + 1e-5f);
        if (n < NN) {
            float4 v = acc[j];
            float4 o;
            o.x = (v.x - mu) * rs * gq.x + bq.x;
            o.y = (v.y - mu) * rs * gq.y + bq.y;
            o.z = (v.z - mu) * rs * gq.z + bq.z;
            o.w = (v.w - mu) * rs * gq.w + bq.w;
            *(float4*)&out[(size_t)n * 128 + c0] = o;
        }
    }
}

extern "C" void kernel_launch(void* const* d_in, const int* in_sizes, int n_in,
                              void* d_out, int out_size, void* d_ws, size_t ws_size,
                              hipStream_t stream) {
    const float* x    = (const float*)d_in[0];
    const int*   ei   = (const int*)d_in[1];
    const float* in_w = (const float*)d_in[2];
    const float* in_b = (const float*)d_in[3];
    const float* ew1  = (const float*)d_in[4];
    const float* eb1  = (const float*)d_in[5];
    const float* ew2  = (const float*)d_in[6];
    const float* eb2  = (const float*)d_in[7];
    const float* cw1  = (const float*)d_in[8];
    const float* cb1  = (const float*)d_in[9];
    const float* cw2  = (const float*)d_in[10];
    const float* cb2  = (const float*)d_in[11];
    const float* lnw  = (const float*)d_in[12];
    const float* lnb  = (const float*)d_in[13];
    const float* fw   = (const float*)d_in[14];
    const float* fb   = (const float*)d_in[15];
    const float* rw   = (const float*)d_in[16];
    const float* rb   = (const float*)d_in[17];
    const float* ow   = (const float*)d_in[18];
    const float* ob   = (const float*)d_in[19];
    float* out = (float*)d_out;

    // workspace layout (bytes), proven budget 128,000,000:
    //   ea   (fp16): NE*64*2  = 102,400,000  @ 0
    //   Ah   (fp16): NN*64*2  =   6,400,000  @ 102,400,000
    //   rows (u16) : NE*2     =   1,600,000  @ 108,800,000
    //   off        : (NN+1)*4 =     200,016  @ 110,400,000
    //   M    (f32) : NN*64*4  =  12,800,000  @ 110,600,016  (ends 123,400,016)
    //   dpos : NE*4 = 3.2M   aliases M      (dead before layer loop)
    //   part : SCAN_BLOCKS*4 aliases M+3.2M (dead before layer loop)
    //   w2f  : 8 KB          aliases M+3.3M (dead before layer loop)
    char* ws = (char*)d_ws;
    __half*         ea   = (__half*)ws;
    __half*         Ah   = (__half*)(ws + 102400000);
    unsigned short* rows = (unsigned short*)(ws + 108800000);
    int*            off  = (int*)(ws + 110400000);
    float*          M    = (float*)(ws + 110600016);
    int*            dpos = (int*)M;
    int*            part = (int*)((char*)M + 3200000);
    __half*         w2f  = (__half*)((char*)M + 3300000);

    (void)hipMemsetAsync(off, 0, (NN + 1) * sizeof(int), stream);
    k_deg<<<NE / 256, 256, 0, stream>>>(ei, off);
    k_scanA<<<SCAN_BLOCKS, 256, 0, stream>>>(off, part);
    k_scanB<<<1, 256, 0, stream>>>(part);
    k_scanC<<<SCAN_BLOCKS, 256, 0, stream>>>(off, part);
    k_scatter<<<NE / 256, 256, 0, stream>>>(ei, off, rows, dpos);
    k_prep<<<1, 256, 0, stream>>>(ew2, w2f);
    k_input<<<NN / 4, 256, 0, stream>>>(x, in_w, in_b, Ah);
    k_edge<<<NE / 256, 256, 0, stream>>>(x, ei, ew1, eb1, eb2, w2f, dpos, ea);

    const int nodeBlocks = (NN + 63) / 64;     // 782
    for (int l = 0; l < 4; ++l) {
        k_agg<<<NN / 4, 256, 0, stream>>>(Ah, ea, rows, off, M);
        k_node<<<nodeBlocks, 256, 0, stream>>>(Ah, M,
            cw1 + (size_t)l * 4096, cb1 + (size_t)l * 64,
            cw2 + (size_t)l * 4096, cb2 + (size_t)l * 64,
            lnw + (size_t)l * 64,   lnb + (size_t)l * 64);
    }
    k_final<<<(NN + 31) / 32, 256, 0, stream>>>(Ah, fw, fb, rw, rb, ow, ob, out);
}

// Round 8
// 477.407 us; speedup vs baseline: 6.9303x; 1.0636x over previous
//
#include <hip/hip_runtime.h>
#include <hip/hip_fp16.h>
#include <stdint.h>

#define NN 50000
#define NE 800000
#define SCAN_BLOCKS 196   // 196*256 = 50176 >= NN

typedef _Float16 half8v __attribute__((ext_vector_type(8)));
typedef float f32x4 __attribute__((ext_vector_type(4)));

static __device__ __forceinline__ __half2 u2h2(unsigned int u) {
    union { unsigned int u; __half2 h; } c; c.u = u; return c.h;
}
static __device__ __forceinline__ unsigned int h22u(__half2 h) {
    union { __half2 h; unsigned int u; } c; c.h = h; return c.u;
}

static __device__ __forceinline__ float4 fma4(float4 a, float s, float4 w) {
    a.x = fmaf(s, w.x, a.x); a.y = fmaf(s, w.y, a.y);
    a.z = fmaf(s, w.z, a.z); a.w = fmaf(s, w.w, a.w);
    return a;
}
// acc[8] += relu(h + e); h/e = 16B of packed fp16, math in fp32
static __device__ __forceinline__ void acc8(float* acc, float4 hv, float4 ev) {
    const unsigned int* hu = (const unsigned int*)&hv;
    const unsigned int* eu = (const unsigned int*)&ev;
    #pragma unroll
    for (int q = 0; q < 4; ++q) {
        float2 hf = __half22float2(u2h2(hu[q]));
        float2 ef = __half22float2(u2h2(eu[q]));
        acc[q * 2]     += fmaxf(hf.x + ef.x, 0.f);
        acc[q * 2 + 1] += fmaxf(hf.y + ef.y, 0.f);
    }
}

// ---------- CSR build ----------
__global__ __launch_bounds__(256) void k_deg(const int* __restrict__ ei, int* __restrict__ offcur) {
    int e = blockIdx.x * 256 + threadIdx.x;
    atomicAdd(&offcur[ei[NE + e]], 1);
}

__global__ __launch_bounds__(256) void k_scanA(const int* __restrict__ off, int* __restrict__ part) {
    __shared__ int s[256];
    int t = threadIdx.x;
    int idx = blockIdx.x * 256 + t;
    int d = (idx < NN) ? off[idx] : 0;
    s[t] = d; __syncthreads();
    for (int o = 128; o > 0; o >>= 1) {
        if (t < o) s[t] += s[t + o];
        __syncthreads();
    }
    if (t == 0) part[blockIdx.x] = s[0];
}

__global__ __launch_bounds__(256) void k_scanB(int* __restrict__ part) {
    __shared__ int s[256];
    int t = threadIdx.x;
    int d = (t < SCAN_BLOCKS) ? part[t] : 0;
    s[t] = d; __syncthreads();
    #pragma unroll
    for (int o = 1; o < 256; o <<= 1) {
        int v = (t >= o) ? s[t - o] : 0;
        __syncthreads();
        s[t] += v;
        __syncthreads();
    }
    if (t < SCAN_BLOCKS) part[t] = s[t] - d;   // exclusive
}

__global__ __launch_bounds__(256) void k_scanC(int* __restrict__ off, const int* __restrict__ part) {
    __shared__ int s[256];
    int t = threadIdx.x;
    int idx = blockIdx.x * 256 + t;
    int d = (idx < NN) ? off[idx] : 0;
    s[t] = d; __syncthreads();
    #pragma unroll
    for (int o = 1; o < 256; o <<= 1) {
        int v = (t >= o) ? s[t - o] : 0;
        __syncthreads();
        s[t] += v;
        __syncthreads();
    }
    if (idx < NN) off[idx] = s[t] - d + part[blockIdx.x];
}

// ---------- weight prep: ew2 -> fp16 MFMA B-fragments (once) ----------
__global__ __launch_bounds__(256) void k_prep(const float* __restrict__ ew2, __half* __restrict__ w2f) {
    int tid = threadIdx.x;
    for (int i = tid; i < 4096; i += 256) {
        int k = i >> 6, n = i & 63;
        int kt = k >> 5, kin = k & 31;
        int quad = kin >> 3, j = kin & 7;
        int nt = n >> 4, nin = n & 15;
        w2f[(size_t)((kt * 4 + nt) * 64 + quad * 16 + nin) * 8 + j] = __float2half(ew2[i]);
    }
}

// ---------- h init (fp16 shadow store) ----------
__global__ __launch_bounds__(256) void k_input(const float* __restrict__ x,
        const float* __restrict__ in_w, const float* __restrict__ in_b,
        __half* __restrict__ Ah) {
    int n = blockIdx.x * 4 + (threadIdx.x >> 6);
    int k = threadIdx.x & 63;
    const float* xr = x + (size_t)n * 3;
    float v = in_b[k] + xr[0] * in_w[k] + xr[1] * in_w[64 + k] + xr[2] * in_w[128 + k];
    Ah[(size_t)n * 64 + k] = __float2half(v);
}

// ---------- edge MLP -> ea (fp16) via f16 MFMA, FUSED CSR scatter ----------
// pos = atomicAdd(off[col]); rows[pos] = row; ea[pos] = edge-MLP output.
__global__ __launch_bounds__(256) void k_edge(const float* __restrict__ x,
        const int* __restrict__ ei,
        const float* __restrict__ ew1, const float* __restrict__ eb1,
        const float* __restrict__ eb2, const __half* __restrict__ w2f,
        int* __restrict__ offcur, unsigned short* __restrict__ rows,
        __half* __restrict__ ea) {
    __shared__ float s_w1[128], s_b1[64], s_b2[64];
    __shared__ float s_rx[256], s_ry[256];
    __shared__ int s_pos[256];
    __shared__ __half s_d[4][16][80];   // per-wave staging
    int tid = threadIdx.x, lane = tid & 63, w = tid >> 6;

    half8v bf[8];
    {
        const half8v* W2F = (const half8v*)w2f;
        #pragma unroll
        for (int f = 0; f < 8; ++f) bf[f] = W2F[f * 64 + lane];
    }
    if (tid < 128) s_w1[tid] = ew1[tid];
    if (tid < 64) s_b1[tid] = eb1[tid];
    else if (tid < 128) s_b2[tid - 64] = eb2[tid - 64];
    int eb = blockIdx.x * 256;
    {
        int e = eb + tid;
        int r = ei[e], c = ei[NE + e];
        s_rx[tid] = x[(size_t)c * 3]     - x[(size_t)r * 3];
        s_ry[tid] = x[(size_t)c * 3 + 1] - x[(size_t)r * 3 + 1];
        int pos = atomicAdd(&offcur[c], 1);
        rows[pos] = (unsigned short)r;
        s_pos[tid] = pos;
    }
    __syncthreads();

    int lm = lane & 15, lq = lane >> 4;
    #pragma unroll
    for (int t = 0; t < 4; ++t) {
        int ebase = w * 64 + t * 16;
        float rx = s_rx[ebase + lm], ry = s_ry[ebase + lm];
        half8v a0, a1;
        #pragma unroll
        for (int j = 0; j < 8; ++j) {
            int k0 = lq * 8 + j;
            a0[j] = (_Float16)fmaxf(fmaf(rx, s_w1[k0], fmaf(ry, s_w1[64 + k0], s_b1[k0])), 0.f);
            int k1 = k0 + 32;
            a1[j] = (_Float16)fmaxf(fmaf(rx, s_w1[k1], fmaf(ry, s_w1[64 + k1], s_b1[k1])), 0.f);
        }
        f32x4 acc[4];
        #pragma unroll
        for (int nt = 0; nt < 4; ++nt) {
            float b = s_b2[nt * 16 + lm];
            acc[nt][0] = b; acc[nt][1] = b; acc[nt][2] = b; acc[nt][3] = b;
            acc[nt] = __builtin_amdgcn_mfma_f32_16x16x32_f16(a0, bf[nt],     acc[nt], 0, 0, 0);
            acc[nt] = __builtin_amdgcn_mfma_f32_16x16x32_f16(a1, bf[4 + nt], acc[nt], 0, 0, 0);
        }
        // epilogue: C/D layout col=lane&15, row=(lane>>4)*4+reg -> wave-private LDS
        __builtin_amdgcn_wave_barrier();
        #pragma unroll
        for (int nt = 0; nt < 4; ++nt)
            #pragma unroll
            for (int r = 0; r < 4; ++r)
                s_d[w][lq * 4 + r][nt * 16 + lm] = __float2half(acc[nt][r]);
        __builtin_amdgcn_wave_barrier();
        int row = lane >> 2, seg = lane & 3;
        int pos = s_pos[w * 64 + t * 16 + row];
        uint4 v0 = *(const uint4*)&s_d[w][row][seg * 16];
        uint4 v1 = *(const uint4*)&s_d[w][row][seg * 16 + 8];
        uint4* dst = (uint4*)&ea[(size_t)pos * 64 + seg * 16];
        dst[0] = v0;
        dst[1] = v1;
        __builtin_amdgcn_wave_barrier();
    }
}

// ---------- per-layer: gather aggregate ----------
// wave per node; lane = es (8 edge sublanes) x oc (8 channel octets of 16B).
// per 16 edges: two 16B h-loads + two 16B ea-loads per lane, independent.
__global__ __launch_bounds__(256) void k_agg(const __half* __restrict__ Ah,
        const __half* __restrict__ ea, const unsigned short* __restrict__ rows,
        const int* __restrict__ offcur, __half* __restrict__ M) {
    const float4* A4 = (const float4*)Ah;   // 8 fp16 per float4
    const float4* E4 = (const float4*)ea;
    int w = threadIdx.x >> 6, lane = threadIdx.x & 63;
    int es = lane >> 3, oc = lane & 7;
    int n = blockIdx.x * 4 + w;
    int p0 = (n == 0) ? 0 : offcur[n - 1];
    int p1 = offcur[n];
    float acc[8] = {0,0,0,0,0,0,0,0};
    float accB[8] = {0,0,0,0,0,0,0,0};
    for (int base = p0; base < p1; base += 64) {
        int cnt = min(64, p1 - base);
        int rl = (int)rows[base + min(lane, cnt - 1)];
        int j = 0;
        for (; j + 16 <= cnt; j += 16) {
            int i0 = j + es, i1 = j + 8 + es;
            int r0 = __shfl(rl, i0, 64);
            int r1 = __shfl(rl, i1, 64);
            float4 h0 = A4[(size_t)r0 * 8 + oc];
            float4 h1 = A4[(size_t)r1 * 8 + oc];
            float4 e0 = E4[(size_t)(base + i0) * 8 + oc];
            float4 e1 = E4[(size_t)(base + i1) * 8 + oc];
            acc8(acc, h0, e0);
            acc8(accB, h1, e1);
        }
        for (; j < cnt; j += 8) {
            int i0 = j + es;
            bool valid = i0 < cnt;
            int ic = valid ? i0 : (cnt - 1);
            int r0 = __shfl(rl, ic, 64);
            float4 h0 = A4[(size_t)r0 * 8 + oc];
            float4 e0 = E4[(size_t)(base + ic) * 8 + oc];
            if (valid) acc8(acc, h0, e0);
        }
    }
    #pragma unroll
    for (int q = 0; q < 8; ++q) acc[q] += accB[q];
    #pragma unroll
    for (int m = 8; m < 64; m <<= 1) {
        #pragma unroll
        for (int q = 0; q < 8; ++q) acc[q] += __shfl_xor(acc[q], m, 64);
    }
    if (es == 0) {
        float4 sv = A4[(size_t)n * 8 + oc];
        const unsigned int* su = (const unsigned int*)&sv;
        unsigned int o[4];
        #pragma unroll
        for (int q = 0; q < 4; ++q) {
            float2 sf = __half22float2(u2h2(su[q]));
            o[q] = h22u(__floats2half2_rn(sf.x + acc[q * 2], sf.y + acc[q * 2 + 1]));
        }
        *(uint4*)&M[(size_t)n * 64 + oc * 8] = *(uint4*)&o[0];
    }
}

// ---------- per-layer: node MLP + LN + gelu + residual (fp16 A, fp16 M) ----------
__global__ __launch_bounds__(256) void k_node(__half* __restrict__ Ah, const __half* __restrict__ M,
        const float* __restrict__ cw1, const float* __restrict__ cb1,
        const float* __restrict__ cw2, const float* __restrict__ cb2,
        const float* __restrict__ lnw, const float* __restrict__ lnb) {
    __shared__ float s_W1[64 * 64];     // [k][c] row-major
    __shared__ float s_W2[64 * 64];
    __shared__ float s_m[64 * 68];      // [node][k], stride 68
    __shared__ float s_b1[64], s_b2[64], s_g[64], s_bt[64];
    int tid = threadIdx.x;
    for (int i = tid; i < 4096; i += 256) { s_W1[i] = cw1[i]; s_W2[i] = cw2[i]; }
    if (tid < 64) { s_b1[tid] = cb1[tid]; s_g[tid] = lnw[tid]; }
    else if (tid < 128) { s_b2[tid - 64] = cb2[tid - 64]; s_bt[tid - 64] = lnb[tid - 64]; }
    int nb = blockIdx.x * 64;
    {
        const uint4* M4 = (const uint4*)(M + (size_t)nb * 64);   // 8 fp16 per uint4
        #pragma unroll
        for (int q = 0; q < 2; ++q) {
            int i = q * 256 + tid;          // uint4 index within block tile (512 total)
            int nl = i >> 3;
            int k8 = (i & 7) * 8;
            uint4 v = {0, 0, 0, 0};
            if (nb + nl < NN) v = M4[i];
            float* dst = &s_m[nl * 68 + k8];
            const unsigned int* vu = (const unsigned int*)&v;
            #pragma unroll
            for (int p = 0; p < 4; ++p) {
                float2 f = __half22float2(u2h2(vu[p]));
                dst[p * 2] = f.x; dst[p * 2 + 1] = f.y;
            }
        }
    }
    __syncthreads();

    int lane = tid & 63, w = tid >> 6;
    int cq = lane & 15, ng = lane >> 4;
    int rbase = w * 16 + ng * 4;
    int c0 = cq * 4;

    float4 acc[4];
    {
        float4 b1q = *(const float4*)&s_b1[c0];
        acc[0] = b1q; acc[1] = b1q; acc[2] = b1q; acc[3] = b1q;
    }
    #pragma unroll 4
    for (int k4 = 0; k4 < 16; ++k4) {
        float4 m0 = *(const float4*)&s_m[(rbase + 0) * 68 + k4 * 4];
        float4 m1 = *(const float4*)&s_m[(rbase + 1) * 68 + k4 * 4];
        float4 m2 = *(const float4*)&s_m[(rbase + 2) * 68 + k4 * 4];
        float4 m3 = *(const float4*)&s_m[(rbase + 3) * 68 + k4 * 4];
        #pragma unroll
        for (int kk = 0; kk < 4; ++kk) {
            float4 w4 = *(const float4*)&s_W1[(k4 * 4 + kk) * 64 + c0];
            acc[0] = fma4(acc[0], ((const float*)&m0)[kk], w4);
            acc[1] = fma4(acc[1], ((const float*)&m1)[kk], w4);
            acc[2] = fma4(acc[2], ((const float*)&m2)[kk], w4);
            acc[3] = fma4(acc[3], ((const float*)&m3)[kk], w4);
        }
    }
    __builtin_amdgcn_wave_barrier();
    #pragma unroll
    for (int j = 0; j < 4; ++j) {
        float4 u;
        u.x = fmaxf(acc[j].x, 0.f); u.y = fmaxf(acc[j].y, 0.f);
        u.z = fmaxf(acc[j].z, 0.f); u.w = fmaxf(acc[j].w, 0.f);
        *(float4*)&s_m[(rbase + j) * 68 + c0] = u;   // own rows only: wave-local
    }
    __builtin_amdgcn_wave_barrier();

    {
        float4 b2q = *(const float4*)&s_b2[c0];
        acc[0] = b2q; acc[1] = b2q; acc[2] = b2q; acc[3] = b2q;
    }
    #pragma unroll 4
    for (int k4 = 0; k4 < 16; ++k4) {
        float4 m0 = *(const float4*)&s_m[(rbase + 0) * 68 + k4 * 4];
        float4 m1 = *(const float4*)&s_m[(rbase + 1) * 68 + k4 * 4];
        float4 m2 = *(const float4*)&s_m[(rbase + 2) * 68 + k4 * 4];
        float4 m3 = *(const float4*)&s_m[(rbase + 3) * 68 + k4 * 4];
        #pragma unroll
        for (int kk = 0; kk < 4; ++kk) {
            float4 w4 = *(const float4*)&s_W2[(k4 * 4 + kk) * 64 + c0];
            acc[0] = fma4(acc[0], ((const float*)&m0)[kk], w4);
            acc[1] = fma4(acc[1], ((const float*)&m1)[kk], w4);
            acc[2] = fma4(acc[2], ((const float*)&m2)[kk], w4);
            acc[3] = fma4(acc[3], ((const float*)&m3)[kk], w4);
        }
    }

    float4 gq  = *(const float4*)&s_g[c0];
    float4 btq = *(const float4*)&s_bt[c0];
    #pragma unroll
    for (int j = 0; j < 4; ++j) {
        float4 v = acc[j];
        float sum = v.x + v.y + v.z + v.w;
        float sq  = v.x * v.x + v.y * v.y + v.z * v.z + v.w * v.w;
        #pragma unroll
        for (int m = 1; m < 16; m <<= 1) {
            sum += __shfl_xor(sum, m, 64);
            sq  += __shfl_xor(sq, m, 64);
        }
        float mu  = sum * (1.f / 64.f);
        float var = sq * (1.f / 64.f) - mu * mu;
        float rs  = rsqrtf(var + 1e-5f);
        int n = nb + rbase + j;
        if (n < NN) {
            uint2 iu = *(const uint2*)&Ah[(size_t)n * 64 + c0];
            float2 i0 = __half22float2(u2h2(iu.x));
            float2 i1 = __half22float2(u2h2(iu.y));
            float4 o;
            float y;
            y = (v.x - mu) * rs * gq.x + btq.x; o.x = 0.5f * y * (1.f + erff(y * 0.70710678118654752f)) + i0.x;
            y = (v.y - mu) * rs * gq.y + btq.y; o.y = 0.5f * y * (1.f + erff(y * 0.70710678118654752f)) + i0.y;
            y = (v.z - mu) * rs * gq.z + btq.z; o.z = 0.5f * y * (1.f + erff(y * 0.70710678118654752f)) + i1.x;
            y = (v.w - mu) * rs * gq.w + btq.w; o.w = 0.5f * y * (1.f + erff(y * 0.70710678118654752f)) + i1.y;
            uint2 ou;
            ou.x = h22u(__floats2half2_rn(o.x, o.y));
            ou.y = h22u(__floats2half2_rn(o.z, o.w));
            *(uint2*)&Ah[(size_t)n * 64 + c0] = ou;
        }
    }
}

// ---------- final: out = LN(h@(fw+rw) + (fb+rb); ow, ob) ----------
__global__ __launch_bounds__(256) void k_final(const __half* __restrict__ Ah,
        const float* __restrict__ fw, const float* __restrict__ fb,
        const float* __restrict__ rw, const float* __restrict__ rb,
        const float* __restrict__ ow, const float* __restrict__ ob,
        float* __restrict__ out) {
    __shared__ float s_W[64 * 128];     // [k][c] row-major, combined fw+rw
    __shared__ float s_h[32 * 68];
    __shared__ float s_b[128];
    __shared__ float s_red[32][4];
    int tid = threadIdx.x;
    for (int i = tid; i < 8192; i += 256) s_W[i] = fw[i] + rw[i];
    if (tid < 128) s_b[tid] = fb[tid] + rb[tid];
    int nb = blockIdx.x * 32;
    for (int i = tid; i < 2048; i += 256) {
        int nl = i >> 6, k = i & 63;
        int n = nb + nl;
        s_h[nl * 68 + k] = (n < NN) ? __half2float(Ah[(size_t)n * 64 + k]) : 0.f;
    }
    __syncthreads();

    int lane = tid & 63, w = tid >> 6;
    int chh = w & 1, nh = w >> 1;
    int cq = lane & 15, ng = lane >> 4;
    int c0 = chh * 64 + cq * 4;
    int rbase = nh * 16 + ng * 4;

    float4 acc[4];
    {
        float4 bq = *(const float4*)&s_b[c0];
        acc[0] = bq; acc[1] = bq; acc[2] = bq; acc[3] = bq;
    }
    #pragma unroll 4
    for (int k4 = 0; k4 < 16; ++k4) {
        float4 m0 = *(const float4*)&s_h[(rbase + 0) * 68 + k4 * 4];
        float4 m1 = *(const float4*)&s_h[(rbase + 1) * 68 + k4 * 4];
        float4 m2 = *(const float4*)&s_h[(rbase + 2) * 68 + k4 * 4];
        float4 m3 = *(const float4*)&s_h[(rbase + 3) * 68 + k4 * 4];
        #pragma unroll
        for (int kk = 0; kk < 4; ++kk) {
            float4 w4 = *(const float4*)&s_W[(k4 * 4 + kk) * 128 + c0];
            acc[0] = fma4(acc[0], ((const float*)&m0)[kk], w4);
            acc[1] = fma4(acc[1], ((const float*)&m1)[kk], w4);
            acc[2] = fma4(acc[2], ((const float*)&m2)[kk], w4);
            acc[3] = fma4(acc[3], ((const float*)&m3)[kk], w4);
        }
    }
    #pragma unroll
    for (int j = 0; j < 4; ++j) {
        float4 v = acc[j];
        float sum = v.x + v.y + v.z + v.w;
        float sq  = v.x * v.x + v.y * v.y + v.z * v.z + v.w * v.w;
        #pragma unroll
        for (int m = 1; m < 16; m <<= 1) {
            sum += __shfl_xor(sum, m, 64);
            sq  += __shfl_xor(sq, m, 64);
        }
        if (cq == 0) {
            s_red[rbase + j][chh * 2]     = sum;
            s_red[rbase + j][chh * 2 + 1] = sq;
        }
    }
    __syncthreads();
    float4 gq = *(const float4*)&ow[c0];
    float4 bq = *(const float4*)&ob[c0];
    #pragma unroll
    for (int j = 0; j < 4; ++j) {
        int nl = rbase + j;
        int n = nb + nl;
        float tsum = s_red[nl][0] + s_red[nl][2];
        float tsq  = s_red[nl][1] + s_red[nl][3];
        float mu  = tsum * (1.f / 128.f);
        float var = tsq * (1.f / 128.f) - mu * mu;
        float rs  = rsqrtf(var + 1e-5f);
        if (n < NN) {
            float4 v = acc[j];
            float4 o;
            o.x = (v.x - mu) * rs * gq.x + bq.x;
            o.y = (v.y - mu) * rs * gq.y + bq.y;
            o.z = (v.z - mu) * rs * gq.z + bq.z;
            o.w = (v.w - mu) * rs * gq.w + bq.w;
            *(float4*)&out[(size_t)n * 128 + c0] = o;
        }
    }
}

extern "C" void kernel_launch(void* const* d_in, const int* in_sizes, int n_in,
                              void* d_out, int out_size, void* d_ws, size_t ws_size,
                              hipStream_t stream) {
    const float* x    = (const float*)d_in[0];
    const int*   ei   = (const int*)d_in[1];
    const float* in_w = (const float*)d_in[2];
    const float* in_b = (const float*)d_in[3];
    const float* ew1  = (const float*)d_in[4];
    const float* eb1  = (const float*)d_in[5];
    const float* ew2  = (const float*)d_in[6];
    const float* eb2  = (const float*)d_in[7];
    const float* cw1  = (const float*)d_in[8];
    const float* cb1  = (const float*)d_in[9];
    const float* cw2  = (const float*)d_in[10];
    const float* cb2  = (const float*)d_in[11];
    const float* lnw  = (const float*)d_in[12];
    const float* lnb  = (const float*)d_in[13];
    const float* fw   = (const float*)d_in[14];
    const float* fb   = (const float*)d_in[15];
    const float* rw   = (const float*)d_in[16];
    const float* rb   = (const float*)d_in[17];
    const float* ow   = (const float*)d_in[18];
    const float* ob   = (const float*)d_in[19];
    float* out = (float*)d_out;

    // workspace layout (bytes), proven budget 128,000,000:
    //   ea   (fp16): NE*64*2  = 102,400,000  @ 0
    //   Ah   (fp16): NN*64*2  =   6,400,000  @ 102,400,000
    //   rows (u16) : NE*2     =   1,600,000  @ 108,800,000
    //   off        : (NN+1)*4 =     200,016  @ 110,400,000
    //   M    (fp16): NN*64*2  =   6,400,000  @ 110,600,016  (ends 117,000,016)
    //   part : SCAN_BLOCKS*4 aliases M       (dead before layer loop)
    //   w2f  : 8 KB          aliases M+100KB (dead before layer loop)
    char* ws = (char*)d_ws;
    __half*         ea   = (__half*)ws;
    __half*         Ah   = (__half*)(ws + 102400000);
    unsigned short* rows = (unsigned short*)(ws + 108800000);
    int*            off  = (int*)(ws + 110400000);
    __half*         M    = (__half*)(ws + 110600016);
    int*            part = (int*)M;
    __half*         w2f  = (__half*)((char*)M + 100000);

    (void)hipMemsetAsync(off, 0, (NN + 1) * sizeof(int), stream);
    k_deg<<<NE / 256, 256, 0, stream>>>(ei, off);
    k_scanA<<<SCAN_BLOCKS, 256, 0, stream>>>(off, part);
    k_scanB<<<1, 256, 0, stream>>>(part);
    k_scanC<<<SCAN_BLOCKS, 256, 0, stream>>>(off, part);
    k_prep<<<1, 256, 0, stream>>>(ew2, w2f);
    k_input<<<NN / 4, 256, 0, stream>>>(x, in_w, in_b, Ah);
    k_edge<<<NE / 256, 256, 0, stream>>>(x, ei, ew1, eb1, eb2, w2f, off, rows, ea);

    const int nodeBlocks = (NN + 63) / 64;     // 782
    for (int l = 0; l < 4; ++l) {
        k_agg<<<NN / 4, 256, 0, stream>>>(Ah, ea, rows, off, M);
        k_node<<<nodeBlocks, 256, 0, stream>>>(Ah, M,
            cw1 + (size_t)l * 4096, cb1 + (size_t)l * 64,
            cw2 + (size_t)l * 4096, cb2 + (size_t)l * 64,
            lnw + (size_t)l * 64,   lnb + (size_t)l * 64);
    }
    k_final<<<(NN + 31) / 32, 256, 0, stream>>>(Ah, fw, fb, rw, rb, ow, ob, out);
}